// Round 11
// baseline (1569.940 us; speedup 1.0000x reference)
//
#include <hip/hip_runtime.h>

typedef unsigned short u16;
typedef __attribute__((ext_vector_type(8))) short short8;
typedef __attribute__((ext_vector_type(8))) unsigned short ushort8;
typedef __attribute__((ext_vector_type(4))) unsigned short us4;
typedef __attribute__((ext_vector_type(4))) float f32x4;
typedef __attribute__((ext_vector_type(2))) float f32x2;
typedef __attribute__((ext_vector_type(2))) unsigned int uint2v;

#define DEV __device__ __forceinline__

DEV float bf2f(u16 u){ union{unsigned int i; float f;} v; v.i = ((unsigned int)u)<<16u; return v.f; }
DEV u16 f2bf(float f){ union{float f; unsigned int i;} v; v.f=f; unsigned int r = v.i + 0x7FFFu + ((v.i>>16)&1u); return (u16)(r>>16); }

DEV void gload16(const u16* g, u16* l){
  __builtin_amdgcn_global_load_lds((const __attribute__((address_space(1))) void*)g,
                                   (__attribute__((address_space(3))) void*)l, 16, 0, 0);
}

DEV float wsum(float v){
  v += __shfl_xor(v, 32, 64);
  v += __shfl_xor(v, 16, 64);
  v += __shfl_xor(v, 8, 64);
  v += __shfl_xor(v, 4, 64);
  v += __shfl_xor(v, 2, 64);
  v += __shfl_xor(v, 1, 64);
  return v;
}

#if __has_builtin(__builtin_amdgcn_permlane16_swap) && __has_builtin(__builtin_amdgcn_permlane32_swap)
DEV float qsum(float v){
  unsigned u = __float_as_uint(v);
  uint2v a = __builtin_amdgcn_permlane16_swap(u, u, false, false);
  float s = __uint_as_float(a[0]) + __uint_as_float(a[1]);
  unsigned u2 = __float_as_uint(s);
  uint2v bsw = __builtin_amdgcn_permlane32_swap(u2, u2, false, false);
  return __uint_as_float(bsw[0]) + __uint_as_float(bsw[1]);
}
#else
DEV float qsum(float v){
  v += __shfl_xor(v, 16, 64);
  v += __shfl_xor(v, 32, 64);
  return v;
}
#endif

// exact element v[lane^32]: proven shfl only (R3 post-mortem).
DEV float swap32(float v){ return __shfl_xor(v, 32, 64); }

// raw workgroup barrier: drain own LDS ops only
#define BARS() do{ asm volatile("s_waitcnt lgkmcnt(0)" ::: "memory"); \
  __builtin_amdgcn_s_barrier(); __builtin_amdgcn_sched_barrier(0); }while(0)

// ---------------- LN over rows of 2048 (f32 in), one row per WAVE ----------------
__global__ __launch_bounds__(256) void ln_row(
    const float* __restrict__ in, const float* __restrict__ w, const float* __restrict__ bb,
    float eps, u16* __restrict__ outb)
{
  const int wv = threadIdx.x>>6, lane = threadIdx.x&63;
  const int row = blockIdx.x*4 + wv;
  const float* p = in + (size_t)row*2048 + lane*4;
  f32x4 a[8];
  #pragma unroll
  for(int j=0;j<8;j++) a[j] = *(const f32x4*)(p + j*256);
  float s = 0.f;
  #pragma unroll
  for(int j=0;j<8;j++) s += a[j][0]+a[j][1]+a[j][2]+a[j][3];
  s = wsum(s);
  float mu = s*(1.f/2048.f);
  float vs = 0.f;
  #pragma unroll
  for(int j=0;j<8;j++)
    #pragma unroll
    for(int r=0;r<4;r++){ float d=a[j][r]-mu; vs += d*d; }
  vs = wsum(vs);
  float rstd = rsqrtf(vs*(1.f/2048.f) + eps);
  #pragma unroll
  for(int j=0;j<8;j++){
    f32x4 wj = *(const f32x4*)(w  + j*256 + lane*4);
    f32x4 bj = *(const f32x4*)(bb + j*256 + lane*4);
    us4 o;
    #pragma unroll
    for(int r=0;r<4;r++) o[r] = f2bf((a[j][r]-mu)*rstd*wj[r] + bj[r]);
    *(us4*)(outb + (size_t)row*2048 + j*256 + lane*4) = o;
  }
}

// ---------------- LN over rows of 2048 (bf16 in), one row per WAVE ----------------
__global__ __launch_bounds__(256) void ln_rowb(
    const u16* __restrict__ in, const float* __restrict__ w, const float* __restrict__ bb,
    float eps, u16* __restrict__ outb)
{
  const int wv = threadIdx.x>>6, lane = threadIdx.x&63;
  const int row = blockIdx.x*4 + wv;
  const u16* p = in + (size_t)row*2048 + lane*4;
  f32x4 a[8];
  #pragma unroll
  for(int j=0;j<8;j++){
    us4 u = *(const us4*)(p + j*256);
    #pragma unroll
    for(int r=0;r<4;r++) a[j][r] = bf2f(u[r]);
  }
  float s = 0.f;
  #pragma unroll
  for(int j=0;j<8;j++) s += a[j][0]+a[j][1]+a[j][2]+a[j][3];
  s = wsum(s);
  float mu = s*(1.f/2048.f);
  float vs = 0.f;
  #pragma unroll
  for(int j=0;j<8;j++)
    #pragma unroll
    for(int r=0;r<4;r++){ float d=a[j][r]-mu; vs += d*d; }
  vs = wsum(vs);
  float rstd = rsqrtf(vs*(1.f/2048.f) + eps);
  #pragma unroll
  for(int j=0;j<8;j++){
    f32x4 wj = *(const f32x4*)(w  + j*256 + lane*4);
    f32x4 bj = *(const f32x4*)(bb + j*256 + lane*4);
    us4 o;
    #pragma unroll
    for(int r=0;r<4;r++) o[r] = f2bf((a[j][r]-mu)*rstd*wj[r] + bj[r]);
    *(us4*)(outb + (size_t)row*2048 + j*256 + lane*4) = o;
  }
}

// ---------------- transpose + cast fp32 (K x N) -> bf16 (N x K), 3 tensors ----------------
__global__ __launch_bounds__(256) void transpose_cast3(
    const float* __restrict__ s0, u16* __restrict__ d0v, int K0, int N0,
    const float* __restrict__ s1, u16* __restrict__ d1v, int K1, int N1,
    const float* __restrict__ s2, u16* __restrict__ d2v, int K2, int N2)
{
  const int z = blockIdx.z;
  const float* src = (z==0)? s0 : (z==1)? s1 : s2;
  u16* dst = (z==0)? d0v : (z==1)? d1v : d2v;
  const int K = (z==0)? K0 : (z==1)? K1 : K2;
  const int N = (z==0)? N0 : (z==1)? N1 : N2;
  const int kb = blockIdx.x*32, nb = blockIdx.y*32;
  if (kb >= K || nb >= N) return;
  __shared__ float tile[32][33];
  const int tx = threadIdx.x & 31, ty = threadIdx.x >> 5; // 32 x 8
  #pragma unroll
  for(int i=0;i<4;i++){
    int k = ty + i*8;
    tile[k][tx] = src[(size_t)(kb+k)*N + nb + tx];
  }
  __syncthreads();
  #pragma unroll
  for(int i=0;i<4;i++){
    int nn = ty + i*8;
    dst[(size_t)(nb+nn)*K + kb + tx] = f2bf(tile[tx][nn]);
  }
}

// cast lr_w (32 x 2048) into rows [0..31] of a 256x2048 block, zero the rest
__global__ __launch_bounds__(256) void cast_lrw(const float* __restrict__ lrw, u16* __restrict__ dst)
{
  int i = blockIdx.x*256 + threadIdx.x;       // 256*2048 total
  if (i < 32*2048) dst[i] = f2bf(lrw[i]);
  else dst[i] = 0;
}

// rope tables (pos 0..15, d 0..63) + tok vector
__global__ void rope_init(const float* __restrict__ tio, float* __restrict__ cosb,
                          float* __restrict__ sinb, float* __restrict__ tokb)
{
  int t = blockIdx.x*256 + threadIdx.x;
  if (t < 1024){
    int p = t>>6, d = t&63;
    float inv = powf(10000.f, -(float)(2*(d&31))/64.f);
    float fr = (float)p * inv;
    cosb[t] = cosf(fr);
    sinb[t] = sinf(fr);
  }
  if (blockIdx.x==0 && threadIdx.x<16)
    tokb[threadIdx.x] = fmaxf(1.f/(float)(threadIdx.x+1) + tio[threadIdx.x], 0.f);
}

// ================== 256x256 8-phase bf16 GEMM tile (BK=64, 8 waves) ==================
// EPI: 1 = +resid(f32) -> bf16; 2 = +bias,relu -> bf16; 3 = +bias,+residb(bf16) -> f32;
//      4 = plain -> bf16
#define MM(MI,NI,AA,BB) acc[MI][NI] = __builtin_amdgcn_mfma_f32_16x16x32_bf16(AA, BB, acc[MI][NI], 0, 0, 0)

#define RD_A(D,KH,MF) (*(const short8*)(ldsb + ((D)<<16) + ((KH)<<14) + (wm<<13) + ((MF)<<10) + loff))
#define RD_B(D,KH,NF) (*(const short8*)(ldsb + ((D)<<16) + 32768 + ((KH)<<14) + (wn<<12) + ((NF)<<10) + loff))

#define PHASE(D,KH,MH,RB,STG,VM) { \
  __builtin_amdgcn_sched_barrier(0); \
  if (RB){ b0 = RD_B(D,KH,0); b1 = RD_B(D,KH,1); b2 = RD_B(D,KH,2); b3 = RD_B(D,KH,3); } \
  short8 a0 = RD_A(D,KH,4*(MH)+0); \
  short8 a1 = RD_A(D,KH,4*(MH)+1); \
  short8 a2 = RD_A(D,KH,4*(MH)+2); \
  short8 a3 = RD_A(D,KH,4*(MH)+3); \
  STG; \
  __builtin_amdgcn_sched_barrier(0); \
  __builtin_amdgcn_s_barrier(); \
  asm volatile("s_waitcnt lgkmcnt(0)" ::: "memory"); \
  __builtin_amdgcn_sched_barrier(0); \
  __builtin_amdgcn_s_setprio(1); \
  MM(4*(MH)+0,0,a0,b0); MM(4*(MH)+1,0,a1,b0); MM(4*(MH)+2,0,a2,b0); MM(4*(MH)+3,0,a3,b0); \
  MM(4*(MH)+0,1,a0,b1); MM(4*(MH)+1,1,a1,b1); MM(4*(MH)+2,1,a2,b1); MM(4*(MH)+3,1,a3,b1); \
  MM(4*(MH)+0,2,a0,b2); MM(4*(MH)+1,2,a1,b2); MM(4*(MH)+2,2,a2,b2); MM(4*(MH)+3,2,a3,b2); \
  MM(4*(MH)+0,3,a0,b3); MM(4*(MH)+1,3,a1,b3); MM(4*(MH)+2,3,a2,b3); MM(4*(MH)+3,3,a3,b3); \
  __builtin_amdgcn_s_setprio(0); \
  if (VM){ asm volatile("s_waitcnt vmcnt(8)" ::: "memory"); } \
  __builtin_amdgcn_sched_barrier(0); \
  __builtin_amdgcn_s_barrier(); \
}

template<int EPI>
DEV void gemm_tile(const u16* A, const u16* Bt,
                   float* C, u16* Cb,
                   const float* bias, const float* resid, const u16* residb,
                   int Nld, int Nreal, int K, int bm, int bn, u16* lds)
{
  const int t = threadIdx.x, lane = t&63, wv = t>>6;
  const int wm = wv>>2, wn = wv&3;          // 2 (M) x 4 (N) waves
  const int fr = lane&15, kq = lane>>4;

  f32x4 acc[8][4];
  #pragma unroll
  for(int i=0;i<8;i++)
    #pragma unroll
    for(int j=0;j<4;j++) acc[i][j]=(f32x4){0.f,0.f,0.f,0.f};

  const u16* gA = A  + (size_t)(bm*256)*K;
  const u16* gB = Bt + (size_t)(bn*256)*K;

  const int Ls   = (t&7) ^ ((t>>3)&7);
  const int rstg = ((t>>3)<<1) | (Ls>>2);
  const int cstg = (Ls&3)<<3;
  u16* const ldsw = lds + (wv<<9);

  const int Plane = (((fr&1)<<2) | kq) ^ (fr>>1);
  const int loff  = ((fr>>1)<<7) | (Plane<<4);
  const char* const ldsb = (const char*)lds;

  auto stA = [&](int d, int kh, int kts){
    u16* lb = ldsw + (d<<15) + (kh<<13);
    const u16* g = gA + (size_t)rstg*K + kts + (kh<<5) + cstg;
    gload16(g, lb);
    gload16(g + ((size_t)K<<7), lb + 4096);
  };
  auto stB = [&](int d, int kh, int kts){
    u16* lb = ldsw + (d<<15) + 16384 + (kh<<13);
    const u16* g = gB + (size_t)rstg*K + kts + (kh<<5) + cstg;
    gload16(g, lb);
    gload16(g + ((size_t)K<<7), lb + 4096);
  };

  stA(0,0,0); stB(0,0,0); stA(0,1,0); stB(0,1,0); stA(1,0,64); stB(1,0,64);
  asm volatile("s_waitcnt vmcnt(8)" ::: "memory");
  __builtin_amdgcn_sched_barrier(0);
  __builtin_amdgcn_s_barrier();

  for (int kt = 0; kt < K; kt += 128){
    const int ktp = (kt+128 < K) ? kt+128 : 0;
    const int ktq = (kt+192 < K) ? kt+192 : kt+192-K;
    short8 b0={0},b1={0},b2={0},b3={0};
    PHASE(0,0,0,1, stA(1,1,kt+64), 0)
    PHASE(0,0,1,0, stB(1,1,kt+64), 1)
    PHASE(0,1,0,1, stA(0,0,ktp),   0)
    PHASE(0,1,1,0, stB(0,0,ktp),   1)
    PHASE(1,0,0,1, stA(0,1,ktp),   0)
    PHASE(1,0,1,0, stB(0,1,ktp),   1)
    PHASE(1,1,0,1, stA(1,0,ktq),   0)
    PHASE(1,1,1,0, stB(1,0,ktq),   1)
  }

  const int cr = (lane>>4)<<2, cc = lane&15;
  #pragma unroll
  for(int mi=0;mi<8;mi++){
    #pragma unroll
    for(int ni=0;ni<4;ni++){
      const int row0 = bm*256 + wm*128 + mi*16 + cr;
      const int col  = bn*256 + wn*64  + ni*16 + cc;
      if (col < Nreal){
        #pragma unroll
        for(int rr=0;rr<4;rr++){
          size_t idx = (size_t)(row0+rr)*Nld + col;
          float v = acc[mi][ni][rr];
          if (EPI==1) { v += resid[idx]; Cb[idx] = f2bf(v); }
          else if (EPI==2){ v += bias[col]; v = fmaxf(v, 0.f); Cb[idx] = f2bf(v); }
          else if (EPI==3){ v += bias[col]; v += bf2f(residb[idx]); C[idx] = v; }
          else { Cb[idx] = f2bf(v); }   // EPI==4
        }
      }
    }
  }
}

template<int EPI>
__global__ __launch_bounds__(512, 2) void gemm256(
    const u16* __restrict__ A, const u16* __restrict__ Bt,
    float* __restrict__ C, u16* __restrict__ Cb,
    const float* __restrict__ bias, const float* __restrict__ resid,
    const u16* __restrict__ residb,
    int Nld, int Nreal, int K, int ntN)
{
  extern __shared__ u16 lds[];
  int bid = blockIdx.x;
  {
    int nwg = gridDim.x;                    // bijective XCD swizzle
    int q = nwg>>3, r = nwg&7;
    int x = bid&7, l = bid>>3;
    bid = (x<r) ? (x*(q+1)+l) : (r*(q+1)+(x-r)*q+l);
  }
  gemm_tile<EPI>(A, Bt, C, Cb, bias, resid, residb, Nld, Nreal, K, bid/ntN, bid%ntN, lds);
}

// ================== merged QKV-GEMM producer + TTT scan consumer ==================
// 256 blocks: 0..127 = GEMM workers (items 0..671, stride 128, batch-round-robin
// M-tile order), 128..255 = scan blocks, each produces ONE late tile (672+idx)
// then scans (b,h). Per-M-tile completion counters (25 N-tiles each): release
// atomicAdd after __threadfence; consumer acquire-polls before each 16-minibatch
// window. Deadlock-free: workers never wait; scan blocks produce before waiting.
// Scan LDS (87KB) overlays the 128KB dynamic GEMM buffer.
#define W1LD 72
#define XLD  72
#define GTLD 40
#define EKLD 40
#define EALD 40
#define TD2  68
#define W1SZ 4608   // 64*W1LD
#define XSZ  1152   // 16*XLD
#define EKSZ 2560   // 64*EKLD
#define GTSZ 2560   // 64*GTLD
#define EASZ 640    // 16*EALD
#define TDSZ 1088   // 16*TD2

__global__ __launch_bounds__(512, 2) void qkv_scan(
    const u16* __restrict__ Abf, const u16* __restrict__ Bt, u16* __restrict__ XQKV,
    int* __restrict__ cnts,
    const float* __restrict__ ropec, const float* __restrict__ ropes,
    const float* __restrict__ tokp,
    const float* __restrict__ nw, const float* __restrict__ nb,
    const float* __restrict__ lrb,
    const float* __restrict__ W1i, const float* __restrict__ b1i,
    u16* __restrict__ Y)
{
  extern __shared__ u16 lds[];
  const int t = threadIdx.x;

  auto flagtile = [&](int mt){
    __threadfence();
    __syncthreads();
    if (t==0) __hip_atomic_fetch_add(&cnts[mt], 1, __ATOMIC_RELEASE, __HIP_MEMORY_SCOPE_AGENT);
  };

  if (blockIdx.x < 128){
    // ---------------- GEMM workers ----------------
    for (int w = blockIdx.x; w < 672; w += 128){
      int mi = w/25, nt = w - mi*25;
      int mt = ((mi&3)<<3) + (mi>>2);
      gemm_tile<4>(Abf, Bt, nullptr, XQKV, nullptr, nullptr, nullptr, 6272, 6272, 2048, mt, nt, lds);
      flagtile(mt);
      __syncthreads();
    }
    return;
  }

  // scan block produces its ONE late tile first (windows 6-7 tail items)
  {
    int w = 672 + (blockIdx.x - 128);
    int mi = w/25, nt = w - mi*25;
    int mt = ((mi&3)<<3) + (mi>>2);
    gemm_tile<4>(Abf, Bt, nullptr, XQKV, nullptr, nullptr, nullptr, 6272, 6272, 2048, mt, nt, lds);
    flagtile(mt);
    __syncthreads();
  }

  // ---------------- TTT scan (R10 structure, LDS overlaid) ----------------
  const int blk = blockIdx.x - 128, b = blk>>5, h = blk&31;
  const int lane = t&63, wv = t>>6;
  const int fr = lane&15, quad = lane>>4;
  const bool isStager = (wv>=4);
  const int sm = wv-4;

  u16*  const W1bf_ = lds;                 // [2][W1SZ]
  u16*  const xqbf_ = lds + 9216;          // [3][XSZ]
  u16*  const xkbf_ = lds + 12672;         // [3][XSZ]
  u16*  const exkT_ = lds + 16128;         // [3][EKSZ]
  u16*  const gqT_  = lds + 23808;         // [2][GTSZ]
  u16*  const etA_  = lds + 28928;         // [2][EASZ]
  float* const tgT_ = (float*)(lds + 30208);  // [3][TDSZ]
  float* const xqT_ = tgT_ + 3264;            // [3][TDSZ]
  float* const b1s_ = xqT_ + 3264;            // [64]
  float* const lrs_ = b1s_ + 64;              // [3][16]

  auto waitm = [&](int mt){
    if (t==0){
      while (__hip_atomic_load(&cnts[mt], __ATOMIC_ACQUIRE, __HIP_MEMORY_SCOPE_AGENT) < 25)
        __builtin_amdgcn_s_sleep(8);
    }
    __syncthreads();
    __threadfence();
  };

  const float lrbh = lrb[h];
  const float ct = tokp[15]*(1.f/64.f);
  const float sg = (lane<32)? -1.f : 1.f;

  f32x2 lwr[16];
  #pragma unroll
  for(int m=0;m<4;m++)
    #pragma unroll
    for(int r=0;r<4;r++){
      int d = m*16+quad*4+r;
      lwr[m*4+r] = (f32x2){nw[h*64+d], nb[h*64+d]};
    }
  float tki[4];
  #pragma unroll
  for(int r=0;r<4;r++) tki[r] = tokp[quad*4+r];

  float ccj[4], ssj[4];
  f32x4 wf0, wf1, wf2, wf3;
  u16 Pq[4], Pk[4], Pv[4], Pl[4];
  if (isStager){
    #pragma unroll
    for(int j=0;j<4;j++){
      ccj[j] = ropec[(sm*4+j)*64 + lane];
      ssj[j] = ropes[(sm*4+j)*64 + lane];
    }
    const float* wsrc = W1i + (size_t)h*4096;
    #pragma unroll
    for(int r=0;r<4;r++){
      int d = sm*16+quad*4+r;
      wf0[r] = wsrc[( 0+fr)*64 + d];
      wf1[r] = wsrc[(16+fr)*64 + d];
      wf2[r] = wsrc[(32+fr)*64 + d];
      wf3[r] = wsrc[(48+fr)*64 + d];
    }
    #pragma unroll
    for(int r=0;r<4;r++){
      int d = sm*16+quad*4+r;
      W1bf_[d*W1LD +  0 + fr] = f2bf(wf0[r]);
      W1bf_[d*W1LD + 16 + fr] = f2bf(wf1[r]);
      W1bf_[d*W1LD + 32 + fr] = f2bf(wf2[r]);
      W1bf_[d*W1LD + 48 + fr] = f2bf(wf3[r]);
    }
  }
  for(int i=t;i<64*24;i+=512){
    int rr=i/24, cp=16+i%24;
    gqT_[rr*GTLD+cp]=0; gqT_[GTSZ + rr*GTLD+cp]=0;
    exkT_[rr*EKLD+cp]=0; exkT_[EKSZ + rr*EKLD+cp]=0; exkT_[2*EKSZ + rr*EKLD+cp]=0;
  }
  for(int i=t;i<16*24;i+=512){
    int rr=i/24, cp=16+i%24;
    etA_[rr*EALD+cp]=0; etA_[EASZ + rr*EALD+cp]=0;
  }
  if (t<64) b1s_[t]=b1i[h*64+t];

  auto loadP = [&](int n){
    const size_t rb = (size_t)b*2048 + n*16;
    #pragma unroll
    for(int j=0;j<4;j++){
      const u16* p = XQKV + (rb+sm*4+j)*6272 + h*64 + lane;
      Pq[j]=p[0]; Pk[j]=p[2048]; Pv[j]=p[4096];
      Pl[j]=XQKV[(rb+sm*4+j)*6272 + 6144 + h];
    }
  };
  auto stage4 = [&](int slot){
    #pragma unroll
    for(int j=0;j<4;j++){
      const int i = sm*4+j;
      float q=bf2f(Pq[j]), k=bf2f(Pk[j]), v=bf2f(Pv[j]);
      float qr = q*ccj[j] + sg*swap32(q)*ssj[j];
      float kr = k*ccj[j] + sg*swap32(k)*ssj[j];
      float lr = 1.f/(1.f + expf(-(bf2f(Pl[j]) + lrbh)));
      xqbf_[slot*XSZ + i*XLD+lane] = f2bf(qr);
      xkbf_[slot*XSZ + i*XLD+lane] = f2bf(kr);
      exkT_[slot*EKSZ + lane*EKLD+i] = f2bf(-ct*lr*kr);
      tgT_[slot*TDSZ + i*TD2+lane] = v - kr;
      xqT_[slot*TDSZ + i*TD2+lane] = qr;
      if (lane==0) lrs_[slot*16+i]=lr;
    }
  };

  // window 0 of this batch must be complete before prologue reads XQKV
  waitm(b*8);
  if (isStager){
    loadP(0);
    stage4(0);
    loadP(1);
  }
  __syncthreads();

  const f32x4 fzero = (f32x4){0.f,0.f,0.f,0.f};

  f32x4 zqP0=fzero, zqP1=fzero, zqP2=fzero, zqP3=fzero;
  f32x4 b1qP0=fzero, b1qP1=fzero, b1qP2=fzero, b1qP3=fzero;

  auto do_out = [&](int p2, int p3, size_t rb){
    short8 be = *(const short8*)&etA_[p2*EASZ + fr*EALD + quad*8];
    f32x4 c20,c21,c22,c23;
    c20 = __builtin_amdgcn_mfma_f32_16x16x32_bf16(*(const short8*)&gqT_[p2*GTSZ + ( 0+fr)*GTLD + quad*8], be, fzero, 0,0,0);
    c21 = __builtin_amdgcn_mfma_f32_16x16x32_bf16(*(const short8*)&gqT_[p2*GTSZ + (16+fr)*GTLD + quad*8], be, fzero, 0,0,0);
    c22 = __builtin_amdgcn_mfma_f32_16x16x32_bf16(*(const short8*)&gqT_[p2*GTSZ + (32+fr)*GTLD + quad*8], be, fzero, 0,0,0);
    c23 = __builtin_amdgcn_mfma_f32_16x16x32_bf16(*(const short8*)&gqT_[p2*GTSZ + (48+fr)*GTLD + quad*8], be, fzero, 0,0,0);
    f32x4 xqv0 = *(const f32x4*)&xqT_[p3*TDSZ + fr*TD2 +  0 + quad*4];
    f32x4 xqv1 = *(const f32x4*)&xqT_[p3*TDSZ + fr*TD2 + 16 + quad*4];
    f32x4 xqv2 = *(const f32x4*)&xqT_[p3*TDSZ + fr*TD2 + 32 + quad*4];
    f32x4 xqv3 = *(const f32x4*)&xqT_[p3*TDSZ + fr*TD2 + 48 + quad*4];
    f32x4 zb0,zb1,zb2,zb3;
    float s1=0.f, s2=0.f;
    #pragma unroll
    for(int r=0;r<4;r++){
      zb0[r] = zqP0[r] + b1qP0[r] + c20[r];
      zb1[r] = zqP1[r] + b1qP1[r] + c21[r];
      zb2[r] = zqP2[r] + b1qP2[r] + c22[r];
      zb3[r] = zqP3[r] + b1qP3[r] + c23[r];
      s1 += zb0[r]+zb1[r]+zb2[r]+zb3[r];
      s2 += zb0[r]*zb0[r]+zb1[r]*zb1[r]+zb2[r]*zb2[r]+zb3[r]*zb3[r];
    }
    s1 = qsum(s1); s2 = qsum(s2);
    float mu = s1*(1.f/64.f);
    float var = s2*(1.f/64.f) - mu*mu;
    float rstd = rsqrtf(var + 1e-6f);
    #pragma unroll
    for(int m=0;m<4;m++){
      f32x4* zp = (m==0)?&zb0:(m==1)?&zb1:(m==2)?&zb2:&zb3;
      const f32x4* xp = (m==0)?&xqv0:(m==1)?&xqv1:(m==2)?&xqv2:&xqv3;
      us4 o;
      #pragma unroll
      for(int r=0;r<4;r++){
        f32x2 wb = lwr[m*4+r];
        float xh = ((*zp)[r] - mu)*rstd;
        o[r] = f2bf((*xp)[r] + xh*wb[0] + wb[1]);
      }
      *(us4*)&Y[(rb+fr)*2048 + h*64 + m*16 + quad*4] = o;
    }
  };

  int c3 = 0;
  for(int n=0;n<128;n++){
    const int cur2 = n&1, pb2 = cur2^1;
    const int cur3 = c3;
    const int nxt3 = (c3==2)? 0 : c3+1;
    const int pb3  = (c3==0)? 2 : c3-1;
    const size_t rbase = (size_t)b*2048 + n*16;

    // window gate for the prefetch issued this iteration (minibatch n+2)
    if (n < 126 && ((n+2)&15)==0) waitm(b*8 + ((n+2)>>4));

    // ---------------- region X ----------------
    if (wv < 2){
      f32x4 b1v0 = *(const f32x4*)&b1s_[ 0+quad*4];
      f32x4 b1v1 = *(const f32x4*)&b1s_[16+quad*4];
      f32x4 b1v2 = *(const f32x4*)&b1s_[32+quad*4];
      f32x4 b1v3 = *(const f32x4*)&b1s_[48+quad*4];
      f32x4 tgv0 = *(const f32x4*)&tgT_[cur3*TDSZ + fr*TD2 +  0 + quad*4];
      f32x4 tgv1 = *(const f32x4*)&tgT_[cur3*TDSZ + fr*TD2 + 16 + quad*4];
      f32x4 tgv2 = *(const f32x4*)&tgT_[cur3*TDSZ + fr*TD2 + 32 + quad*4];
      f32x4 tgv3 = *(const f32x4*)&tgT_[cur3*TDSZ + fr*TD2 + 48 + quad*4];
      short8 bk0 = *(const short8*)&xkbf_[cur3*XSZ + fr*XLD + quad*8];
      short8 bk1 = *(const short8*)&xkbf_[cur3*XSZ + fr*XLD + 32 + quad*8];
      f32x4 z0,z1,z2,z3;
      z0 = __builtin_amdgcn_mfma_f32_16x16x32_bf16(*(const short8*)&W1bf_[cur2*W1SZ + ( 0+fr)*W1LD + quad*8],      bk0, fzero, 0,0,0);
      z0 = __builtin_amdgcn_mfma_f32_16x16x32_bf16(*(const short8*)&W1bf_[cur2*W1SZ + ( 0+fr)*W1LD + 32 + quad*8], bk1, z0,    0,0,0);
      z1 = __builtin_amdgcn_mfma_f32_16x16x32_bf16(*(const short8*)&W1bf_[cur2*W1SZ + (16+fr)*W1LD + quad*8],      bk0, fzero, 0,0,0);
      z1 = __builtin_amdgcn_mfma_f32_16x16x32_bf16(*(const short8*)&W1bf_[cur2*W1SZ + (16+fr)*W1LD + 32 + quad*8], bk1, z1,    0,0,0);
      z2 = __builtin_amdgcn_mfma_f32_16x16x32_bf16(*(const short8*)&W1bf_[cur2*W1SZ + (32+fr)*W1LD + quad*8],      bk0, fzero, 0,0,0);
      z2 = __builtin_amdgcn_mfma_f32_16x16x32_bf16(*(const short8*)&W1bf_[cur2*W1SZ + (32+fr)*W1LD + 32 + quad*8], bk1, z2,    0,0,0);
      z3 = __builtin_amdgcn_mfma_f32_16x16x32_bf16(*(const short8*)&W1bf_[cur2*W1SZ + (48+fr)*W1LD + quad*8],      bk0, fzero, 0,0,0);
      z3 = __builtin_amdgcn_mfma_f32_16x16x32_bf16(*(const short8*)&W1bf_[cur2*W1SZ + (48+fr)*W1LD + 32 + quad*8], bk1, z3,    0,0,0);
      f32x4 xh0,xh1,xh2,xh3;
      {
        float s1=0.f, s2=0.f;
        #pragma unroll
        for(int r=0;r<4;r++){
          z0[r] += b1v0[r];
          z1[r] += b1v1[r];
          z2[r] += b1v2[r];
          z3[r] += b1v3[r];
          s1 += z0[r]+z1[r]+z2[r]+z3[r];
          s2 += z0[r]*z0[r]+z1[r]*z1[r]+z2[r]*z2[r]+z3[r]*z3[r];
        }
        s1 = qsum(s1); s2 = qsum(s2);
        float mu = s1*(1.f/64.f);
        float var = s2*(1.f/64.f) - mu*mu;
        float rstd = rsqrtf(var + 1e-6f);
        float u1=0.f, u2=0.f;
        #pragma unroll
        for(int m=0;m<4;m++){
          f32x4* zp = (m==0)?&z0:(m==1)?&z1:(m==2)?&z2:&z3;
          f32x4* xp = (m==0)?&xh0:(m==1)?&xh1:(m==2)?&xh2:&xh3;
          const f32x4* tp = (m==0)?&tgv0:(m==1)?&tgv1:(m==2)?&tgv2:&tgv3;
          #pragma unroll
          for(int r=0;r<4;r++){
            f32x2 wb = lwr[m*4+r];
            float xh = ((*zp)[r] - mu)*rstd;
            float gx = (wb[0]*xh + wb[1] - (*tp)[r])*wb[0];
            (*xp)[r] = xh;
            (*zp)[r] = gx;
            u1 += gx; u2 += gx*xh;
          }
        }
        u1 = qsum(u1); u2 = qsum(u2);
        const float c64 = rstd*(1.f/64.f);
        #pragma unroll
        for(int m=0;m<4;m++){
          f32x4* zp = (m==0)?&z0:(m==1)?&z1:(m==2)?&z2:&z3;
          f32x4* xp = (m==0)?&xh0:(m==1)?&xh1:(m==2)?&xh2:&xh3;
          #pragma unroll
          for(int r=0;r<4;r++)
            (*zp)[r] = (64.f*(*zp)[r] - u1 - (*xp)[r]*u2)*c64;   // gradT
        }
      }
      f32x4 zA = (wv==0)? z0 : z2;
      f32x4 zB = (wv==0)? z1 : z3;
      const int rb0 = wv*32;
      #pragma unroll
      for(int r=0;r<4;r++){
        gqT_[cur2*GTSZ + (rb0+quad*4+r)*GTLD + fr]    = f2bf(zA[r]);
        gqT_[cur2*GTSZ + (rb0+16+quad*4+r)*GTLD + fr] = f2bf(zB[r]);
      }
    }
    else if (wv == 2){
      short8 bq0 = *(const short8*)&xqbf_[cur3*XSZ + fr*XLD + quad*8];
      short8 bq1 = *(const short8*)&xqbf_[cur3*XSZ + fr*XLD + 32 + quad*8];
      f32x4 zqN0,zqN1,zqN2,zqN3;
      zqN0 = __builtin_amdgcn_mfma_f32_16x16x32_bf16(*(const short8*)&W1bf_[cur2*W1SZ + ( 0+fr)*W1LD + quad*8],      bq0, fzero, 0,0,0);
      zqN0 = __builtin_amdgcn_mfma_f32_16x16x32_bf16(*(const short8*)&W1bf_[cur2*W1SZ + ( 0+fr)*W1LD + 32 + quad*8], bq1, zqN0,  0,0,0);
      zqN1 = __builtin_amdgcn_mfma_f32_16x16x32_bf16(*(const short8*)&W1bf_[cur2*W1SZ + (16+fr)*W1LD + quad*8],      bq0, fzero, 0,0,0);
      zqN1 = __builtin_amdgcn_mfma_f32_16x16x32_bf16(*(const short8*)&W1bf_[cur2*W1SZ + (16+fr)*W1LD + 32 + quad*8], bq1, zqN1,  0,0,0);
      zqN2 = __builtin_amdgcn_mfma_f32_16x16x32_bf16(*(const short8*)&W1bf_[cur2*W1SZ + (32+fr)*W1LD + quad*8],      bq0, fzero, 0,0,0);
      zqN2 = __builtin_amdgcn_mfma_f32_16x16x32_bf16(*(const short8*)&W1bf_[cur2*W1SZ + (32+fr)*W1LD + 32 + quad*8], bq1, zqN2,  0,0,0);
      zqN3 = __builtin_amdgcn_mfma_f32_16x16x32_bf16(*(const short8*)&W1bf_[cur2*W1SZ + (48+fr)*W1LD + quad*8],      bq0, fzero, 0,0,0);
      zqN3 = __builtin_amdgcn_mfma_f32_16x16x32_bf16(*(const short8*)&W1bf_[cur2*W1SZ + (48+fr)*W1LD + 32 + quad*8], bq1, zqN3,  0,0,0);
      if (n > 0) do_out(pb2, pb3, rbase - 16);
      zqP0=zqN0; zqP1=zqN1; zqP2=zqN2; zqP3=zqN3;
      b1qP0 = *(const f32x4*)&b1s_[ 0+quad*4];
      b1qP1 = *(const f32x4*)&b1s_[16+quad*4];
      b1qP2 = *(const f32x4*)&b1s_[32+quad*4];
      b1qP3 = *(const f32x4*)&b1s_[48+quad*4];
    }
    else if (wv == 3){
      short8 aq0 = *(const short8*)&xqbf_[cur3*XSZ + fr*XLD + quad*8];
      short8 aq1 = *(const short8*)&xqbf_[cur3*XSZ + fr*XLD + 32 + quad*8];
      short8 bk0 = *(const short8*)&xkbf_[cur3*XSZ + fr*XLD + quad*8];
      short8 bk1 = *(const short8*)&xkbf_[cur3*XSZ + fr*XLD + 32 + quad*8];
      f32x4 at;
      at = __builtin_amdgcn_mfma_f32_16x16x32_bf16(aq0, bk0, fzero, 0,0,0);
      at = __builtin_amdgcn_mfma_f32_16x16x32_bf16(aq1, bk1, at,    0,0,0);
      float lrj = lrs_[cur3*16+fr]*(1.f/64.f);
      #pragma unroll
      for(int r=0;r<4;r++){
        int i = quad*4 + r;
        float val = (fr <= i) ? -tki[r]*lrj*(1.f + at[r]) : 0.f;
        etA_[cur2*EASZ + i*EALD + fr] = f2bf(val);
      }
    }
    else {
      if (n < 127) stage4(nxt3);
      if (n < 126) loadP(n+2);
    }
    BARS();

    // ---------------- region Y ----------------
    if (isStager){
      short8 ga = *(const short8*)&gqT_[cur2*GTSZ + (sm*16+fr)*GTLD + quad*8];
      short8 e0 = *(const short8*)&exkT_[cur3*EKSZ + ( 0+fr)*EKLD + quad*8];
      short8 e1 = *(const short8*)&exkT_[cur3*EKSZ + (16+fr)*EKLD + quad*8];
      short8 e2 = *(const short8*)&exkT_[cur3*EKSZ + (32+fr)*EKLD + quad*8];
      short8 e3 = *(const short8*)&exkT_[cur3*EKSZ + (48+fr)*EKLD + quad*8];
      wf0 = __builtin_amdgcn_mfma_f32_16x16x32_bf16(ga, e0, wf0, 0,0,0);
      wf1 = __builtin_amdgcn_mfma_f32_16x16x32_bf16(ga, e1, wf1, 0,0,0);
      wf2 = __builtin_amdgcn_mfma_f32_16x16x32_bf16(ga, e2, wf2, 0,0,0);
      wf3 = __builtin_amdgcn_mfma_f32_16x16x32_bf16(ga, e3, wf3, 0,0,0);
      #pragma unroll
      for(int r=0;r<4;r++){
        int d = sm*16+quad*4+r;
        W1bf_[pb2*W1SZ + d*W1LD +  0 + fr] = f2bf(wf0[r]);
        W1bf_[pb2*W1SZ + d*W1LD + 16 + fr] = f2bf(wf1[r]);
        W1bf_[pb2*W1SZ + d*W1LD + 32 + fr] = f2bf(wf2[r]);
        W1bf_[pb2*W1SZ + d*W1LD + 48 + fr] = f2bf(wf3[r]);
      }
    }
    else if (wv == 3){
      const int d = lane;
      short8 g0 = *(const short8*)&gqT_[cur2*GTSZ + d*GTLD + 0];
      short8 g1 = *(const short8*)&gqT_[cur2*GTSZ + d*GTLD + 8];
      float s = 0.f;
      #pragma unroll
      for(int j=0;j<8;j++) s += lrs_[cur3*16+j]   * bf2f((u16)g0[j]);
      #pragma unroll
      for(int j=0;j<8;j++) s += lrs_[cur3*16+8+j] * bf2f((u16)g1[j]);
      b1s_[d] -= ct * s;
    }
    BARS();
    c3 = nxt3;
  }

  // epilogue: output of the last step (n=127): parity2 = 1, slot3 = 1
  if (wv == 2) do_out(1, 1, (size_t)b*2048 + 127*16);
}

// ---------------- host launch ----------------
extern "C" void kernel_launch(void* const* d_in, const int* in_sizes, int n_in,
                              void* d_out, int out_size, void* d_ws, size_t ws_size,
                              hipStream_t stream)
{
  const float* enc   = (const float*)d_in[0];
  const float* ln1w  = (const float*)d_in[1];
  const float* ln1b  = (const float*)d_in[2];
  const float* qw    = (const float*)d_in[3];
  const float* kw    = (const float*)d_in[4];
  const float* vw    = (const float*)d_in[5];
  const float* ow    = (const float*)d_in[6];
  const float* lrw   = (const float*)d_in[7];
  const float* lrb   = (const float*)d_in[8];
  const float* tio   = (const float*)d_in[9];
  const float* tnw   = (const float*)d_in[10];
  const float* tnb   = (const float*)d_in[11];
  const float* W1i   = (const float*)d_in[12];
  const float* b1i   = (const float*)d_in[13];
  const float* postw = (const float*)d_in[14];
  const float* postb = (const float*)d_in[15];
  const float* flnw  = (const float*)d_in[16];
  const float* flnb  = (const float*)d_in[17];
  const float* w1f   = (const float*)d_in[18];
  const float* b1f   = (const float*)d_in[19];
  const float* w2f   = (const float*)d_in[20];
  const float* b2f   = (const float*)d_in[21];
  float* out = (float*)d_out;

  char* ws = (char*)d_ws;
  size_t off = 0;
  auto alloc = [&](size_t bytes)->void*{ void* p = ws + off; off += (bytes + 255) & ~(size_t)255; return p; };
  u16*   regA  = (u16*)  alloc(8192ull*2048*2);   // x_bf -> ypost_bf -> z_bf
  u16*   wqkvT = (u16*)  alloc(6400ull*2048*2);   // [qT|kT|vT|lr(32)+zeros..6400); later oT/w1fT/w2fT
  u16*   XQKV  = (u16*)  alloc(8192ull*6272*2);   // later: h_bf
  u16*   ybb   = (u16*)  alloc(8192ull*2048*2);   // scan output y (bf16)
  u16*   y2b   = (u16*)  alloc(8192ull*2048*2);   // y2 = o-proj + enc (bf16)
  float* ropec = (float*)alloc(1024*4);
  float* ropes = (float*)alloc(1024*4);
  float* tokb  = (float*)alloc(64*4);
  int*   cnts  = (int*)  alloc(128);              // 32 per-M-tile counters

  u16* oT   = wqkvT;
  u16* w1fT = wqkvT + 2048ull*2048;
  u16* w2fT = w1fT + 1024ull*2048;
  u16* hbf  = XQKV;

  static bool s_attr = false;
  if (!s_attr){
    s_attr = true;
    (void)hipFuncSetAttribute(reinterpret_cast<const void*>(qkv_scan),  hipFuncAttributeMaxDynamicSharedMemorySize, 131072);
    (void)hipFuncSetAttribute(reinterpret_cast<const void*>(gemm256<1>), hipFuncAttributeMaxDynamicSharedMemorySize, 131072);
    (void)hipFuncSetAttribute(reinterpret_cast<const void*>(gemm256<2>), hipFuncAttributeMaxDynamicSharedMemorySize, 131072);
    (void)hipFuncSetAttribute(reinterpret_cast<const void*>(gemm256<3>), hipFuncAttributeMaxDynamicSharedMemorySize, 131072);
  }

  rope_init<<<4, 256, 0, stream>>>(tio, ropec, ropes, tokb);

  // fused pre-GEMM weight transposes (q,k,v)
  transpose_cast3<<<dim3(64,64,3), 256, 0, stream>>>(
      qw, wqkvT,                2048, 2048,
      kw, wqkvT + 2048ull*2048, 2048, 2048,
      vw, wqkvT + 4096ull*2048, 2048, 2048);
  cast_lrw<<<2048, 256, 0, stream>>>(lrw, wqkvT + 6144ull*2048);

  ln_row<<<2048, 256, 0, stream>>>(enc, ln1w, ln1b, 1e-5f, regA);

  // merged QKV projection (producer) + TTT scan (consumer)
  (void)hipMemsetAsync(cnts, 0, 128, stream);
  qkv_scan<<<256, 512, 131072, stream>>>(regA, wqkvT, XQKV, cnts,
                                         ropec, ropes, tokb, tnw, tnb, lrb, W1i, b1i, ybb);

  // fused post weight transposes (o, w1f, w2f) — reuses wqkvT, so AFTER qkv_scan
  transpose_cast3<<<dim3(64,64,3), 256, 0, stream>>>(
      ow,  oT,   2048, 2048,
      w1f, w1fT, 2048, 1024,
      w2f, w2fT, 1024, 2048);

  // post-LN + O-projection + residual(enc) -> y2b (bf16)
  ln_rowb<<<2048, 256, 0, stream>>>(ybb, postw, postb, 1e-6f, regA);
  gemm256<1><<<32*8, 512, 131072, stream>>>(regA, oT, nullptr, y2b,
                                            nullptr, enc, nullptr, 2048, 2048, 2048, 8);

  // FFN
  ln_rowb<<<2048, 256, 0, stream>>>(y2b, flnw, flnb, 1e-6f, regA);
  gemm256<2><<<32*4, 512, 131072, stream>>>(regA, w1fT, nullptr, hbf,
                                            b1f, nullptr, nullptr, 1024, 1024, 2048, 4);
  gemm256<3><<<32*8, 512, 131072, stream>>>(hbf, w2fT, out, nullptr,
                                            b2f, nullptr, y2b, 2048, 2048, 1024, 8);
}

// Round 12
// 749.196 us; speedup vs baseline: 2.0955x; 2.0955x over previous
//
#include <hip/hip_runtime.h>

typedef unsigned short u16;
typedef __attribute__((ext_vector_type(8))) short short8;
typedef __attribute__((ext_vector_type(8))) unsigned short ushort8;
typedef __attribute__((ext_vector_type(4))) unsigned short us4;
typedef __attribute__((ext_vector_type(4))) float f32x4;
typedef __attribute__((ext_vector_type(2))) float f32x2;
typedef __attribute__((ext_vector_type(2))) unsigned int uint2v;

#define DEV __device__ __forceinline__

DEV float bf2f(u16 u){ union{unsigned int i; float f;} v; v.i = ((unsigned int)u)<<16u; return v.f; }
DEV u16 f2bf(float f){ union{float f; unsigned int i;} v; v.f=f; unsigned int r = v.i + 0x7FFFu + ((v.i>>16)&1u); return (u16)(r>>16); }

DEV void gload16(const u16* g, u16* l){
  __builtin_amdgcn_global_load_lds((const __attribute__((address_space(1))) void*)g,
                                   (__attribute__((address_space(3))) void*)l, 16, 0, 0);
}

DEV float wsum(float v){
  v += __shfl_xor(v, 32, 64);
  v += __shfl_xor(v, 16, 64);
  v += __shfl_xor(v, 8, 64);
  v += __shfl_xor(v, 4, 64);
  v += __shfl_xor(v, 2, 64);
  v += __shfl_xor(v, 1, 64);
  return v;
}

// sum over the 4 lanes sharing (lane&15). permlane pair-sum is
// orientation-agnostic (a[0]+a[1] == v + v[lane^k]) -> safe. (R2-verified.)
#if __has_builtin(__builtin_amdgcn_permlane16_swap) && __has_builtin(__builtin_amdgcn_permlane32_swap)
DEV float qsum(float v){
  unsigned u = __float_as_uint(v);
  uint2v a = __builtin_amdgcn_permlane16_swap(u, u, false, false);
  float s = __uint_as_float(a[0]) + __uint_as_float(a[1]);
  unsigned u2 = __float_as_uint(s);
  uint2v bsw = __builtin_amdgcn_permlane32_swap(u2, u2, false, false);
  return __uint_as_float(bsw[0]) + __uint_as_float(bsw[1]);
}
#else
DEV float qsum(float v){
  v += __shfl_xor(v, 16, 64);
  v += __shfl_xor(v, 32, 64);
  return v;
}
#endif

// exact element v[lane^32]: proven shfl only (R3 post-mortem).
DEV float swap32(float v){ return __shfl_xor(v, 32, 64); }

// raw workgroup barrier: drain own LDS ops only
#define BARS() do{ asm volatile("s_waitcnt lgkmcnt(0)" ::: "memory"); \
  __builtin_amdgcn_s_barrier(); __builtin_amdgcn_sched_barrier(0); }while(0)

// ---------------- LN over rows of 2048 (f32 in), one row per WAVE ----------------
__global__ __launch_bounds__(256) void ln_row(
    const float* __restrict__ in, const float* __restrict__ w, const float* __restrict__ bb,
    float eps, u16* __restrict__ outb)
{
  const int wv = threadIdx.x>>6, lane = threadIdx.x&63;
  const int row = blockIdx.x*4 + wv;
  const float* p = in + (size_t)row*2048 + lane*4;
  f32x4 a[8];
  #pragma unroll
  for(int j=0;j<8;j++) a[j] = *(const f32x4*)(p + j*256);
  float s = 0.f;
  #pragma unroll
  for(int j=0;j<8;j++) s += a[j][0]+a[j][1]+a[j][2]+a[j][3];
  s = wsum(s);
  float mu = s*(1.f/2048.f);
  float vs = 0.f;
  #pragma unroll
  for(int j=0;j<8;j++)
    #pragma unroll
    for(int r=0;r<4;r++){ float d=a[j][r]-mu; vs += d*d; }
  vs = wsum(vs);
  float rstd = rsqrtf(vs*(1.f/2048.f) + eps);
  #pragma unroll
  for(int j=0;j<8;j++){
    f32x4 wj = *(const f32x4*)(w  + j*256 + lane*4);
    f32x4 bj = *(const f32x4*)(bb + j*256 + lane*4);
    us4 o;
    #pragma unroll
    for(int r=0;r<4;r++) o[r] = f2bf((a[j][r]-mu)*rstd*wj[r] + bj[r]);
    *(us4*)(outb + (size_t)row*2048 + j*256 + lane*4) = o;
  }
}

// ---------------- LN over rows of 2048 (bf16 in), one row per WAVE ----------------
// bf16 loads vectorized as short8 (16B/lane, G13)
__global__ __launch_bounds__(256) void ln_rowb(
    const u16* __restrict__ in, const float* __restrict__ w, const float* __restrict__ bb,
    float eps, u16* __restrict__ outb)
{
  const int wv = threadIdx.x>>6, lane = threadIdx.x&63;
  const int row = blockIdx.x*4 + wv;
  const u16* p = in + (size_t)row*2048 + lane*8;
  float a[32];
  #pragma unroll
  for(int j=0;j<4;j++){
    ushort8 u = *(const ushort8*)(p + j*512);
    #pragma unroll
    for(int r=0;r<8;r++) a[j*8+r] = bf2f(u[r]);
  }
  float s = 0.f;
  #pragma unroll
  for(int e=0;e<32;e++) s += a[e];
  s = wsum(s);
  float mu = s*(1.f/2048.f);
  float vs = 0.f;
  #pragma unroll
  for(int e=0;e<32;e++){ float d=a[e]-mu; vs += d*d; }
  vs = wsum(vs);
  float rstd = rsqrtf(vs*(1.f/2048.f) + eps);
  #pragma unroll
  for(int j=0;j<4;j++){
    f32x4 w0 = *(const f32x4*)(w  + j*512 + lane*8);
    f32x4 w1 = *(const f32x4*)(w  + j*512 + lane*8 + 4);
    f32x4 b0 = *(const f32x4*)(bb + j*512 + lane*8);
    f32x4 b1 = *(const f32x4*)(bb + j*512 + lane*8 + 4);
    ushort8 o;
    #pragma unroll
    for(int r=0;r<4;r++) o[r]   = f2bf((a[j*8+r]-mu)*rstd*w0[r] + b0[r]);
    #pragma unroll
    for(int r=0;r<4;r++) o[r+4] = f2bf((a[j*8+4+r]-mu)*rstd*w1[r] + b1[r]);
    *(ushort8*)(outb + (size_t)row*2048 + j*512 + lane*8) = o;
  }
}

// ---------------- transpose + cast fp32 (K x N) -> bf16 (N x K), 3 tensors ----------------
__global__ __launch_bounds__(256) void transpose_cast3(
    const float* __restrict__ s0, u16* __restrict__ d0v, int K0, int N0,
    const float* __restrict__ s1, u16* __restrict__ d1v, int K1, int N1,
    const float* __restrict__ s2, u16* __restrict__ d2v, int K2, int N2)
{
  const int z = blockIdx.z;
  const float* src = (z==0)? s0 : (z==1)? s1 : s2;
  u16* dst = (z==0)? d0v : (z==1)? d1v : d2v;
  const int K = (z==0)? K0 : (z==1)? K1 : K2;
  const int N = (z==0)? N0 : (z==1)? N1 : N2;
  const int kb = blockIdx.x*32, nb = blockIdx.y*32;
  if (kb >= K || nb >= N) return;
  __shared__ float tile[32][33];
  const int tx = threadIdx.x & 31, ty = threadIdx.x >> 5; // 32 x 8
  #pragma unroll
  for(int i=0;i<4;i++){
    int k = ty + i*8;
    tile[k][tx] = src[(size_t)(kb+k)*N + nb + tx];
  }
  __syncthreads();
  #pragma unroll
  for(int i=0;i<4;i++){
    int nn = ty + i*8;
    dst[(size_t)(nb+nn)*K + kb + tx] = f2bf(tile[tx][nn]);
  }
}

// cast lr_w (32 x 2048) into rows [0..31] of a 256x2048 block, zero the rest
__global__ __launch_bounds__(256) void cast_lrw(const float* __restrict__ lrw, u16* __restrict__ dst)
{
  int i = blockIdx.x*256 + threadIdx.x;       // 256*2048 total
  if (i < 32*2048) dst[i] = f2bf(lrw[i]);
  else dst[i] = 0;
}

// rope tables (pos 0..15, d 0..63) + tok vector
__global__ void rope_init(const float* __restrict__ tio, float* __restrict__ cosb,
                          float* __restrict__ sinb, float* __restrict__ tokb)
{
  int t = blockIdx.x*256 + threadIdx.x;
  if (t < 1024){
    int p = t>>6, d = t&63;
    float inv = powf(10000.f, -(float)(2*(d&31))/64.f);
    float fr = (float)p * inv;
    cosb[t] = cosf(fr);
    sinb[t] = sinf(fr);
  }
  if (blockIdx.x==0 && threadIdx.x<16)
    tokb[threadIdx.x] = fmaxf(1.f/(float)(threadIdx.x+1) + tio[threadIdx.x], 0.f);
}

// ================== 256x256 8-phase bf16 GEMM (BK=64, 8 waves) ==================
// EPI: 1 = +resid(f32) -> bf16; 2 = +bias,relu -> bf16; 3 = +bias,+residb(bf16) -> f32;
//      4 = plain -> bf16
#define MM(MI,NI,AA,BB) acc[MI][NI] = __builtin_amdgcn_mfma_f32_16x16x32_bf16(AA, BB, acc[MI][NI], 0, 0, 0)

#define RD_A(D,KH,MF) (*(const short8*)(ldsb + ((D)<<16) + ((KH)<<14) + (wm<<13) + ((MF)<<10) + loff))
#define RD_B(D,KH,NF) (*(const short8*)(ldsb + ((D)<<16) + 32768 + ((KH)<<14) + (wn<<12) + ((NF)<<10) + loff))

#define PHASE(D,KH,MH,RB,STG,VM) { \
  __builtin_amdgcn_sched_barrier(0); \
  if (RB){ b0 = RD_B(D,KH,0); b1 = RD_B(D,KH,1); b2 = RD_B(D,KH,2); b3 = RD_B(D,KH,3); } \
  short8 a0 = RD_A(D,KH,4*(MH)+0); \
  short8 a1 = RD_A(D,KH,4*(MH)+1); \
  short8 a2 = RD_A(D,KH,4*(MH)+2); \
  short8 a3 = RD_A(D,KH,4*(MH)+3); \
  STG; \
  __builtin_amdgcn_sched_barrier(0); \
  __builtin_amdgcn_s_barrier(); \
  asm volatile("s_waitcnt lgkmcnt(0)" ::: "memory"); \
  __builtin_amdgcn_sched_barrier(0); \
  __builtin_amdgcn_s_setprio(1); \
  MM(4*(MH)+0,0,a0,b0); MM(4*(MH)+1,0,a1,b0); MM(4*(MH)+2,0,a2,b0); MM(4*(MH)+3,0,a3,b0); \
  MM(4*(MH)+0,1,a0,b1); MM(4*(MH)+1,1,a1,b1); MM(4*(MH)+2,1,a2,b1); MM(4*(MH)+3,1,a3,b1); \
  MM(4*(MH)+0,2,a0,b2); MM(4*(MH)+1,2,a1,b2); MM(4*(MH)+2,2,a2,b2); MM(4*(MH)+3,2,a3,b2); \
  MM(4*(MH)+0,3,a0,b3); MM(4*(MH)+1,3,a1,b3); MM(4*(MH)+2,3,a2,b3); MM(4*(MH)+3,3,a3,b3); \
  __builtin_amdgcn_s_setprio(0); \
  if (VM){ asm volatile("s_waitcnt vmcnt(8)" ::: "memory"); } \
  __builtin_amdgcn_sched_barrier(0); \
  __builtin_amdgcn_s_barrier(); \
}

template<int EPI>
__global__ __launch_bounds__(512, 2) void gemm256(
    const u16* __restrict__ A, const u16* __restrict__ Bt,
    float* __restrict__ C, u16* __restrict__ Cb,
    const float* __restrict__ bias, const float* __restrict__ resid,
    const u16* __restrict__ residb,
    int Nld, int Nreal, int K, int ntN)
{
  extern __shared__ u16 lds[];
  const int t = threadIdx.x, lane = t&63, wv = t>>6;
  const int wm = wv>>2, wn = wv&3;          // 2 (M) x 4 (N) waves
  const int fr = lane&15, kq = lane>>4;

  int bid = blockIdx.x;
  {
    int nwg = gridDim.x;                    // bijective XCD swizzle
    int q = nwg>>3, r = nwg&7;
    int x = bid&7, l = bid>>3;
    bid = (x<r) ? (x*(q+1)+l) : (r*(q+1)+(x-r)*q+l);
  }
  const int bm = bid/ntN, bn = bid%ntN;

  f32x4 acc[8][4];
  #pragma unroll
  for(int i=0;i<8;i++)
    #pragma unroll
    for(int j=0;j<4;j++) acc[i][j]=(f32x4){0.f,0.f,0.f,0.f};

  const u16* gA = A  + (size_t)(bm*256)*K;
  const u16* gB = Bt + (size_t)(bn*256)*K;

  const int Ls   = (t&7) ^ ((t>>3)&7);
  const int rstg = ((t>>3)<<1) | (Ls>>2);
  const int cstg = (Ls&3)<<3;
  u16* const ldsw = lds + (wv<<9);

  const int Plane = (((fr&1)<<2) | kq) ^ (fr>>1);
  const int loff  = ((fr>>1)<<7) | (Plane<<4);
  const char* const ldsb = (const char*)lds;

  auto stA = [&](int d, int kh, int kts){
    u16* lb = ldsw + (d<<15) + (kh<<13);
    const u16* g = gA + (size_t)rstg*K + kts + (kh<<5) + cstg;
    gload16(g, lb);
    gload16(g + ((size_t)K<<7), lb + 4096);
  };
  auto stB = [&](int d, int kh, int kts){
    u16* lb = ldsw + (d<<15) + 16384 + (kh<<13);
    const u16* g = gB + (size_t)rstg*K + kts + (kh<<5) + cstg;
    gload16(g, lb);
    gload16(g + ((size_t)K<<7), lb + 4096);
  };

  stA(0,0,0); stB(0,0,0); stA(0,1,0); stB(0,1,0); stA(1,0,64); stB(1,0,64);
  asm volatile("s_waitcnt vmcnt(8)" ::: "memory");
  __builtin_amdgcn_sched_barrier(0);
  __builtin_amdgcn_s_barrier();

  for (int kt = 0; kt < K; kt += 128){
    const int ktp = (kt+128 < K) ? kt+128 : 0;
    const int ktq = (kt+192 < K) ? kt+192 : kt+192-K;
    short8 b0={0},b1={0},b2={0},b3={0};
    PHASE(0,0,0,1, stA(1,1,kt+64), 0)
    PHASE(0,0,1,0, stB(1,1,kt+64), 1)
    PHASE(0,1,0,1, stA(0,0,ktp),   0)
    PHASE(0,1,1,0, stB(0,0,ktp),   1)
    PHASE(1,0,0,1, stA(0,1,ktp),   0)
    PHASE(1,0,1,0, stB(0,1,ktp),   1)
    PHASE(1,1,0,1, stA(1,0,ktq),   0)
    PHASE(1,1,1,0, stB(1,0,ktq),   1)
  }

  const int cr = (lane>>4)<<2, cc = lane&15;
  #pragma unroll
  for(int mi=0;mi<8;mi++){
    #pragma unroll
    for(int ni=0;ni<4;ni++){
      const int row0 = bm*256 + wm*128 + mi*16 + cr;
      const int col  = bn*256 + wn*64  + ni*16 + cc;
      if (col < Nreal){
        #pragma unroll
        for(int rr=0;rr<4;rr++){
          size_t idx = (size_t)(row0+rr)*Nld + col;
          float v = acc[mi][ni][rr];
          if (EPI==1) { v += resid[idx]; Cb[idx] = f2bf(v); }
          else if (EPI==2){ v += bias[col]; v = fmaxf(v, 0.f); Cb[idx] = f2bf(v); }
          else if (EPI==3){ v += bias[col]; v += bf2f(residb[idx]); C[idx] = v; }
          else { Cb[idx] = f2bf(v); }   // EPI==4
        }
      }
    }
  }
}

// ================== MFMA TTT scan ==================
// R10 structure (two regions, SIMD-paired roles), bf16 Y output.
//  SIMD0: wave0=chain    + wave4=stager
//  SIMD1: wave1=chain    + wave5=stager
//  SIMD2: wave2=Zq+out   + wave6=stager
//  SIMD3: wave3=At(+b1Y) + wave7=stager
#define W1LD 72
#define XLD  72
#define GTLD 40
#define EKLD 40
#define EALD 40
#define TD2  68

__global__ __launch_bounds__(512, 1) void ttt_scan(
    const u16* __restrict__ XQKV,   // 8192 x 6272 bf16: [q|k|v|lr_pre(32)+pad]
    const float* __restrict__ ropec, const float* __restrict__ ropes,
    const float* __restrict__ tokp,
    const float* __restrict__ nw, const float* __restrict__ nb,
    const float* __restrict__ lrb,
    const float* __restrict__ W1i,  // NH x 64 x 64  (W1i[h][k][d])
    const float* __restrict__ b1i,  // NH x 64
    u16* __restrict__ Y)            // 8192 x 2048 bf16
{
  const int blk = blockIdx.x, b = blk>>5, h = blk&31;
  const int t = threadIdx.x, lane = t&63, wv = t>>6;
  const int fr = lane&15, quad = lane>>4;
  const bool isStager = (wv>=4);
  const int sm = wv-4;                 // 0..3 for stagers (mtile / row-group)

  __shared__ u16 W1bf[2][64*W1LD];     // double-buffered W1t[d][k] bf16
  __shared__ u16 xqbf[3][16*XLD];      // [i][k], slot = minibatch%3
  __shared__ u16 xkbf[3][16*XLD];
  __shared__ u16 exkT[3][64*EKLD];     // [k][j] = -e_j * xk[j][k]
  __shared__ u16 gradTbf[2][64*GTLD];  // [d][j], parity = step&1
  __shared__ u16 etaA[2][16*EALD];     // [i][j], parity = step&1
  __shared__ float tgT2[3][16*TD2];    // [i][d] = (v - xk)[i][d]
  __shared__ float xqT2[3][16*TD2];    // [i][d]
  __shared__ float b1s[64];
  __shared__ float lrs[3][16];

  const float lrbh = lrb[h];
  const float ct = tokp[15]*(1.f/64.f);
  const float sg = (lane<32)? -1.f : 1.f;

  // loop-invariant LN params / tok in registers
  f32x2 lwr[16];
  #pragma unroll
  for(int m=0;m<4;m++)
    #pragma unroll
    for(int r=0;r<4;r++){
      int d = m*16+quad*4+r;
      lwr[m*4+r] = (f32x2){nw[h*64+d], nb[h*64+d]};
    }
  float tki[4];
  #pragma unroll
  for(int r=0;r<4;r++) tki[r] = tokp[quad*4+r];

  // stagers: rope tables for their 4 rows, W1 state (mtile sm), prefetch regs
  float ccj[4], ssj[4];
  f32x4 wf0, wf1, wf2, wf3;
  u16 Pq[4], Pk[4], Pv[4], Pl[4];
  if (isStager){
    #pragma unroll
    for(int j=0;j<4;j++){
      ccj[j] = ropec[(sm*4+j)*64 + lane];
      ssj[j] = ropes[(sm*4+j)*64 + lane];
    }
    const float* wsrc = W1i + (size_t)h*4096;
    #pragma unroll
    for(int r=0;r<4;r++){
      int d = sm*16+quad*4+r;
      wf0[r] = wsrc[( 0+fr)*64 + d];
      wf1[r] = wsrc[(16+fr)*64 + d];
      wf2[r] = wsrc[(32+fr)*64 + d];
      wf3[r] = wsrc[(48+fr)*64 + d];
    }
    #pragma unroll
    for(int r=0;r<4;r++){
      int d = sm*16+quad*4+r;
      W1bf[0][d*W1LD +  0 + fr] = f2bf(wf0[r]);
      W1bf[0][d*W1LD + 16 + fr] = f2bf(wf1[r]);
      W1bf[0][d*W1LD + 32 + fr] = f2bf(wf2[r]);
      W1bf[0][d*W1LD + 48 + fr] = f2bf(wf3[r]);
    }
  }
  // zero pads (cols [16,40) so K=32 fragments see zeros) — all buffers
  for(int i=t;i<64*24;i+=512){
    int rr=i/24, cp=16+i%24;
    gradTbf[0][rr*GTLD+cp]=0; gradTbf[1][rr*GTLD+cp]=0;
    exkT[0][rr*EKLD+cp]=0; exkT[1][rr*EKLD+cp]=0; exkT[2][rr*EKLD+cp]=0;
  }
  for(int i=t;i<16*24;i+=512){
    int rr=i/24, cp=16+i%24;
    etaA[0][rr*EALD+cp]=0; etaA[1][rr*EALD+cp]=0;
  }
  if (t<64) b1s[t]=b1i[h*64+t];

  // stager helpers: load minibatch n rows (sm*4..sm*4+3) into P; stage P -> slot
  auto loadP = [&](int n){
    const size_t rb = (size_t)b*2048 + n*16;
    #pragma unroll
    for(int j=0;j<4;j++){
      const u16* p = XQKV + (rb+sm*4+j)*6272 + h*64 + lane;
      Pq[j]=p[0]; Pk[j]=p[2048]; Pv[j]=p[4096];
      Pl[j]=XQKV[(rb+sm*4+j)*6272 + 6144 + h];
    }
  };
  auto stage4 = [&](int slot){
    #pragma unroll
    for(int j=0;j<4;j++){
      const int i = sm*4+j;
      float q=bf2f(Pq[j]), k=bf2f(Pk[j]), v=bf2f(Pv[j]);
      float qr = q*ccj[j] + sg*swap32(q)*ssj[j];
      float kr = k*ccj[j] + sg*swap32(k)*ssj[j];
      float lr = 1.f/(1.f + expf(-(bf2f(Pl[j]) + lrbh)));
      xqbf[slot][i*XLD+lane] = f2bf(qr);
      xkbf[slot][i*XLD+lane] = f2bf(kr);
      exkT[slot][lane*EKLD+i] = f2bf(-ct*lr*kr);
      tgT2[slot][i*TD2+lane] = v - kr;
      xqT2[slot][i*TD2+lane] = qr;
      if (lane==0) lrs[slot][i]=lr;
    }
  };

  // prologue: stage minibatch 0 into slot 0; prefetch minibatch 1
  if (isStager){
    loadP(0);
    stage4(0);
    loadP(1);
  }
  __syncthreads();

  const f32x4 fzero = (f32x4){0.f,0.f,0.f,0.f};

  // wave-2 carried state (output pipeline depth 1)
  f32x4 zqP0=fzero, zqP1=fzero, zqP2=fzero, zqP3=fzero;
  f32x4 b1qP0=fzero, b1qP1=fzero, b1qP2=fzero, b1qP3=fzero;

  // output chain for step s: parity2 = s&1 (etaA/gradT), slot3 = s%3 (xqT2)
  auto do_out = [&](int p2, int p3, size_t rb){
    short8 be = *(const short8*)&etaA[p2][fr*EALD + quad*8];
    f32x4 c20,c21,c22,c23;
    c20 = __builtin_amdgcn_mfma_f32_16x16x32_bf16(*(const short8*)&gradTbf[p2][( 0+fr)*GTLD + quad*8], be, fzero, 0,0,0);
    c21 = __builtin_amdgcn_mfma_f32_16x16x32_bf16(*(const short8*)&gradTbf[p2][(16+fr)*GTLD + quad*8], be, fzero, 0,0,0);
    c22 = __builtin_amdgcn_mfma_f32_16x16x32_bf16(*(const short8*)&gradTbf[p2][(32+fr)*GTLD + quad*8], be, fzero, 0,0,0);
    c23 = __builtin_amdgcn_mfma_f32_16x16x32_bf16(*(const short8*)&gradTbf[p2][(48+fr)*GTLD + quad*8], be, fzero, 0,0,0);
    f32x4 xqv0 = *(const f32x4*)&xqT2[p3][fr*TD2 +  0 + quad*4];
    f32x4 xqv1 = *(const f32x4*)&xqT2[p3][fr*TD2 + 16 + quad*4];
    f32x4 xqv2 = *(const f32x4*)&xqT2[p3][fr*TD2 + 32 + quad*4];
    f32x4 xqv3 = *(const f32x4*)&xqT2[p3][fr*TD2 + 48 + quad*4];
    f32x4 zb0,zb1,zb2,zb3;
    float s1=0.f, s2=0.f;
    #pragma unroll
    for(int r=0;r<4;r++){
      zb0[r] = zqP0[r] + b1qP0[r] + c20[r];
      zb1[r] = zqP1[r] + b1qP1[r] + c21[r];
      zb2[r] = zqP2[r] + b1qP2[r] + c22[r];
      zb3[r] = zqP3[r] + b1qP3[r] + c23[r];
      s1 += zb0[r]+zb1[r]+zb2[r]+zb3[r];
      s2 += zb0[r]*zb0[r]+zb1[r]*zb1[r]+zb2[r]*zb2[r]+zb3[r]*zb3[r];
    }
    s1 = qsum(s1); s2 = qsum(s2);
    float mu = s1*(1.f/64.f);
    float var = s2*(1.f/64.f) - mu*mu;
    float rstd = rsqrtf(var + 1e-6f);
    #pragma unroll
    for(int m=0;m<4;m++){
      f32x4* zp = (m==0)?&zb0:(m==1)?&zb1:(m==2)?&zb2:&zb3;
      const f32x4* xp = (m==0)?&xqv0:(m==1)?&xqv1:(m==2)?&xqv2:&xqv3;
      us4 o;
      #pragma unroll
      for(int r=0;r<4;r++){
        f32x2 wb = lwr[m*4+r];
        float xh = ((*zp)[r] - mu)*rstd;
        o[r] = f2bf((*xp)[r] + xh*wb[0] + wb[1]);
      }
      *(us4*)&Y[(rb+fr)*2048 + h*64 + m*16 + quad*4] = o;
    }
  };

  int c3 = 0;   // n%3
  for(int n=0;n<128;n++){
    const int cur2 = n&1, pb2 = cur2^1;
    const int cur3 = c3;
    const int nxt3 = (c3==2)? 0 : c3+1;
    const int pb3  = (c3==0)? 2 : c3-1;
    const size_t rbase = (size_t)b*2048 + n*16;

    // ---------------- region X ----------------
    if (wv < 2){
      f32x4 b1v0 = *(const f32x4*)&b1s[ 0+quad*4];
      f32x4 b1v1 = *(const f32x4*)&b1s[16+quad*4];
      f32x4 b1v2 = *(const f32x4*)&b1s[32+quad*4];
      f32x4 b1v3 = *(const f32x4*)&b1s[48+quad*4];
      f32x4 tgv0 = *(const f32x4*)&tgT2[cur3][fr*TD2 +  0 + quad*4];
      f32x4 tgv1 = *(const f32x4*)&tgT2[cur3][fr*TD2 + 16 + quad*4];
      f32x4 tgv2 = *(const f32x4*)&tgT2[cur3][fr*TD2 + 32 + quad*4];
      f32x4 tgv3 = *(const f32x4*)&tgT2[cur3][fr*TD2 + 48 + quad*4];
      // Zk^T = W1t (x) xk : C[d][i], full 64x16 (dup x2: waves 0,1)
      short8 bk0 = *(const short8*)&xkbf[cur3][fr*XLD + quad*8];
      short8 bk1 = *(const short8*)&xkbf[cur3][fr*XLD + 32 + quad*8];
      f32x4 z0,z1,z2,z3;
      z0 = __builtin_amdgcn_mfma_f32_16x16x32_bf16(*(const short8*)&W1bf[cur2][( 0+fr)*W1LD + quad*8],      bk0, fzero, 0,0,0);
      z0 = __builtin_amdgcn_mfma_f32_16x16x32_bf16(*(const short8*)&W1bf[cur2][( 0+fr)*W1LD + 32 + quad*8], bk1, z0,    0,0,0);
      z1 = __builtin_amdgcn_mfma_f32_16x16x32_bf16(*(const short8*)&W1bf[cur2][(16+fr)*W1LD + quad*8],      bk0, fzero, 0,0,0);
      z1 = __builtin_amdgcn_mfma_f32_16x16x32_bf16(*(const short8*)&W1bf[cur2][(16+fr)*W1LD + 32 + quad*8], bk1, z1,    0,0,0);
      z2 = __builtin_amdgcn_mfma_f32_16x16x32_bf16(*(const short8*)&W1bf[cur2][(32+fr)*W1LD + quad*8],      bk0, fzero, 0,0,0);
      z2 = __builtin_amdgcn_mfma_f32_16x16x32_bf16(*(const short8*)&W1bf[cur2][(32+fr)*W1LD + 32 + quad*8], bk1, z2,    0,0,0);
      z3 = __builtin_amdgcn_mfma_f32_16x16x32_bf16(*(const short8*)&W1bf[cur2][(48+fr)*W1LD + quad*8],      bk0, fzero, 0,0,0);
      z3 = __builtin_amdgcn_mfma_f32_16x16x32_bf16(*(const short8*)&W1bf[cur2][(48+fr)*W1LD + 32 + quad*8], bk1, z3,    0,0,0);
      // LN-l2 backward
      f32x4 xh0,xh1,xh2,xh3;
      {
        float s1=0.f, s2=0.f;
        #pragma unroll
        for(int r=0;r<4;r++){
          z0[r] += b1v0[r];
          z1[r] += b1v1[r];
          z2[r] += b1v2[r];
          z3[r] += b1v3[r];
          s1 += z0[r]+z1[r]+z2[r]+z3[r];
          s2 += z0[r]*z0[r]+z1[r]*z1[r]+z2[r]*z2[r]+z3[r]*z3[r];
        }
        s1 = qsum(s1); s2 = qsum(s2);
        float mu = s1*(1.f/64.f);
        float var = s2*(1.f/64.f) - mu*mu;
        float rstd = rsqrtf(var + 1e-6f);
        float u1=0.f, u2=0.f;
        #pragma unroll
        for(int m=0;m<4;m++){
          f32x4* zp = (m==0)?&z0:(m==1)?&z1:(m==2)?&z2:&z3;
          f32x4* xp = (m==0)?&xh0:(m==1)?&xh1:(m==2)?&xh2:&xh3;
          const f32x4* tp = (m==0)?&tgv0:(m==1)?&tgv1:(m==2)?&tgv2:&tgv3;
          #pragma unroll
          for(int r=0;r<4;r++){
            f32x2 wb = lwr[m*4+r];
            float xh = ((*zp)[r] - mu)*rstd;
            float gx = (wb[0]*xh + wb[1] - (*tp)[r])*wb[0];
            (*xp)[r] = xh;
            (*zp)[r] = gx;
            u1 += gx; u2 += gx*xh;
          }
        }
        u1 = qsum(u1); u2 = qsum(u2);
        const float c64 = rstd*(1.f/64.f);
        #pragma unroll
        for(int m=0;m<4;m++){
          f32x4* zp = (m==0)?&z0:(m==1)?&z1:(m==2)?&z2:&z3;
          f32x4* xp = (m==0)?&xh0:(m==1)?&xh1:(m==2)?&xh2:&xh3;
          #pragma unroll
          for(int r=0;r<4;r++)
            (*zp)[r] = (64.f*(*zp)[r] - u1 - (*xp)[r]*u2)*c64;   // gradT
        }
      }
      // wave0 writes mtiles 0,1; wave1 writes 2,3
      f32x4 zA = (wv==0)? z0 : z2;
      f32x4 zB = (wv==0)? z1 : z3;
      const int rb0 = wv*32;
      #pragma unroll
      for(int r=0;r<4;r++){
        gradTbf[cur2][(rb0+quad*4+r)*GTLD + fr]    = f2bf(zA[r]);
        gradTbf[cur2][(rb0+16+quad*4+r)*GTLD + fr] = f2bf(zB[r]);
      }
    }
    else if (wv == 2){
      // Zq(n): independent MFMAs into fresh regs
      short8 bq0 = *(const short8*)&xqbf[cur3][fr*XLD + quad*8];
      short8 bq1 = *(const short8*)&xqbf[cur3][fr*XLD + 32 + quad*8];
      f32x4 zqN0,zqN1,zqN2,zqN3;
      zqN0 = __builtin_amdgcn_mfma_f32_16x16x32_bf16(*(const short8*)&W1bf[cur2][( 0+fr)*W1LD + quad*8],      bq0, fzero, 0,0,0);
      zqN0 = __builtin_amdgcn_mfma_f32_16x16x32_bf16(*(const short8*)&W1bf[cur2][( 0+fr)*W1LD + 32 + quad*8], bq1, zqN0,  0,0,0);
      zqN1 = __builtin_amdgcn_mfma_f32_16x16x32_bf16(*(const short8*)&W1bf[cur2][(16+fr)*W1LD + quad*8],      bq0, fzero, 0,0,0);
      zqN1 = __builtin_amdgcn_mfma_f32_16x16x32_bf16(*(const short8*)&W1bf[cur2][(16+fr)*W1LD + 32 + quad*8], bq1, zqN1,  0,0,0);
      zqN2 = __builtin_amdgcn_mfma_f32_16x16x32_bf16(*(const short8*)&W1bf[cur2][(32+fr)*W1LD + quad*8],      bq0, fzero, 0,0,0);
      zqN2 = __builtin_amdgcn_mfma_f32_16x16x32_bf16(*(const short8*)&W1bf[cur2][(32+fr)*W1LD + 32 + quad*8], bq1, zqN2,  0,0,0);
      zqN3 = __builtin_amdgcn_mfma_f32_16x16x32_bf16(*(const short8*)&W1bf[cur2][(48+fr)*W1LD + quad*8],      bq0, fzero, 0,0,0);
      zqN3 = __builtin_amdgcn_mfma_f32_16x16x32_bf16(*(const short8*)&W1bf[cur2][(48+fr)*W1LD + 32 + quad*8], bq1, zqN3,  0,0,0);
      // output of step n-1
      if (n > 0) do_out(pb2, pb3, rbase - 16);
      // rotate pipeline state
      zqP0=zqN0; zqP1=zqN1; zqP2=zqN2; zqP3=zqN3;
      b1qP0 = *(const f32x4*)&b1s[ 0+quad*4];   // b1 pre-update for step n
      b1qP1 = *(const f32x4*)&b1s[16+quad*4];
      b1qP2 = *(const f32x4*)&b1s[32+quad*4];
      b1qP3 = *(const f32x4*)&b1s[48+quad*4];
    }
    else if (wv == 3){
      // At = xq (x) xk : C[i][j] -> etaA[cur2]
      short8 aq0 = *(const short8*)&xqbf[cur3][fr*XLD + quad*8];
      short8 aq1 = *(const short8*)&xqbf[cur3][fr*XLD + 32 + quad*8];
      short8 bk0 = *(const short8*)&xkbf[cur3][fr*XLD + quad*8];
      short8 bk1 = *(const short8*)&xkbf[cur3][fr*XLD + 32 + quad*8];
      f32x4 at;
      at = __builtin_amdgcn_mfma_f32_16x16x32_bf16(aq0, bk0, fzero, 0,0,0);
      at = __builtin_amdgcn_mfma_f32_16x16x32_bf16(aq1, bk1, at,    0,0,0);
      float lrj = lrs[cur3][fr]*(1.f/64.f);
      #pragma unroll
      for(int r=0;r<4;r++){
        int i = quad*4 + r;
        float val = (fr <= i) ? -tki[r]*lrj*(1.f + at[r]) : 0.f;
        etaA[cur2][i*EALD + fr] = f2bf(val);
      }
    }
    else {
      // stagers (4-7): stage(n+1) into slot nxt3; prefetch minibatch n+2
      if (n < 127) stage4(nxt3);
      if (n < 126) loadP(n+2);
    }
    BARS();

    // ---------------- region Y ----------------
    if (isStager){
      // W1 update: wave owns mtile sm, tiles n=0..3
      short8 ga = *(const short8*)&gradTbf[cur2][(sm*16+fr)*GTLD + quad*8];
      short8 e0 = *(const short8*)&exkT[cur3][( 0+fr)*EKLD + quad*8];
      short8 e1 = *(const short8*)&exkT[cur3][(16+fr)*EKLD + quad*8];
      short8 e2 = *(const short8*)&exkT[cur3][(32+fr)*EKLD + quad*8];
      short8 e3 = *(const short8*)&exkT[cur3][(48+fr)*EKLD + quad*8];
      wf0 = __builtin_amdgcn_mfma_f32_16x16x32_bf16(ga, e0, wf0, 0,0,0);
      wf1 = __builtin_amdgcn_mfma_f32_16x16x32_bf16(ga, e1, wf1, 0,0,0);
      wf2 = __builtin_amdgcn_mfma_f32_16x16x32_bf16(ga, e2, wf2, 0,0,0);
      wf3 = __builtin_amdgcn_mfma_f32_16x16x32_bf16(ga, e3, wf3, 0,0,0);
      #pragma unroll
      for(int r=0;r<4;r++){
        int d = sm*16+quad*4+r;
        W1bf[pb2][d*W1LD +  0 + fr] = f2bf(wf0[r]);
        W1bf[pb2][d*W1LD + 16 + fr] = f2bf(wf1[r]);
        W1bf[pb2][d*W1LD + 32 + fr] = f2bf(wf2[r]);
        W1bf[pb2][d*W1LD + 48 + fr] = f2bf(wf3[r]);
      }
    }
    else if (wv == 3){
      // b1 update: b1s[d] -= ct * sum_j lrs[j] * gradT[d][j]
      const int d = lane;
      short8 g0 = *(const short8*)&gradTbf[cur2][d*GTLD + 0];
      short8 g1 = *(const short8*)&gradTbf[cur2][d*GTLD + 8];
      float s = 0.f;
      #pragma unroll
      for(int j=0;j<8;j++) s += lrs[cur3][j]   * bf2f((u16)g0[j]);
      #pragma unroll
      for(int j=0;j<8;j++) s += lrs[cur3][8+j] * bf2f((u16)g1[j]);
      b1s[d] -= ct * s;
    }
    BARS();
    c3 = nxt3;
  }

  // epilogue: output of the last step (n=127): parity2 = 1, slot3 = 127%3 = 1
  if (wv == 2) do_out(1, 1, (size_t)b*2048 + 127*16);
}

// ---------------- host launch ----------------
extern "C" void kernel_launch(void* const* d_in, const int* in_sizes, int n_in,
                              void* d_out, int out_size, void* d_ws, size_t ws_size,
                              hipStream_t stream)
{
  const float* enc   = (const float*)d_in[0];
  const float* ln1w  = (const float*)d_in[1];
  const float* ln1b  = (const float*)d_in[2];
  const float* qw    = (const float*)d_in[3];
  const float* kw    = (const float*)d_in[4];
  const float* vw    = (const float*)d_in[5];
  const float* ow    = (const float*)d_in[6];
  const float* lrw   = (const float*)d_in[7];
  const float* lrb   = (const float*)d_in[8];
  const float* tio   = (const float*)d_in[9];
  const float* tnw   = (const float*)d_in[10];
  const float* tnb   = (const float*)d_in[11];
  const float* W1i   = (const float*)d_in[12];
  const float* b1i   = (const float*)d_in[13];
  const float* postw = (const float*)d_in[14];
  const float* postb = (const float*)d_in[15];
  const float* flnw  = (const float*)d_in[16];
  const float* flnb  = (const float*)d_in[17];
  const float* w1f   = (const float*)d_in[18];
  const float* b1f   = (const float*)d_in[19];
  const float* w2f   = (const float*)d_in[20];
  const float* b2f   = (const float*)d_in[21];
  float* out = (float*)d_out;

  char* ws = (char*)d_ws;
  size_t off = 0;
  auto alloc = [&](size_t bytes)->void*{ void* p = ws + off; off += (bytes + 255) & ~(size_t)255; return p; };
  u16*   regA  = (u16*)  alloc(8192ull*2048*2);   // x_bf -> ypost_bf -> z_bf
  u16*   wqkvT = (u16*)  alloc(6400ull*2048*2);   // [qT|kT|vT|lr(32)+zeros..6400); later oT/w1fT/w2fT
  u16*   XQKV  = (u16*)  alloc(8192ull*6272*2);   // later: h_bf
  u16*   ybb   = (u16*)  alloc(8192ull*2048*2);   // scan output y (bf16)
  u16*   y2b   = (u16*)  alloc(8192ull*2048*2);   // y2 = o-proj + enc (bf16)
  float* ropec = (float*)alloc(1024*4);
  float* ropes = (float*)alloc(1024*4);
  float* tokb  = (float*)alloc(64*4);

  u16* oT   = wqkvT;
  u16* w1fT = wqkvT + 2048ull*2048;
  u16* w2fT = w1fT + 1024ull*2048;
  u16* hbf  = XQKV;

  static bool s_attr = false;
  if (!s_attr){
    s_attr = true;
    (void)hipFuncSetAttribute(reinterpret_cast<const void*>(gemm256<4>), hipFuncAttributeMaxDynamicSharedMemorySize, 131072);
    (void)hipFuncSetAttribute(reinterpret_cast<const void*>(gemm256<1>), hipFuncAttributeMaxDynamicSharedMemorySize, 131072);
    (void)hipFuncSetAttribute(reinterpret_cast<const void*>(gemm256<2>), hipFuncAttributeMaxDynamicSharedMemorySize, 131072);
    (void)hipFuncSetAttribute(reinterpret_cast<const void*>(gemm256<3>), hipFuncAttributeMaxDynamicSharedMemorySize, 131072);
  }

  rope_init<<<4, 256, 0, stream>>>(tio, ropec, ropes, tokb);

  // fused pre-GEMM weight transposes (q,k,v)
  transpose_cast3<<<dim3(64,64,3), 256, 0, stream>>>(
      qw, wqkvT,                2048, 2048,
      kw, wqkvT + 2048ull*2048, 2048, 2048,
      vw, wqkvT + 4096ull*2048, 2048, 2048);
  cast_lrw<<<2048, 256, 0, stream>>>(lrw, wqkvT + 6144ull*2048);

  ln_row<<<2048, 256, 0, stream>>>(enc, ln1w, ln1b, 1e-5f, regA);

  // QKV + lr projection: logical N=6400 (25 tiles), real cols 6272, ldc 6272
  gemm256<4><<<32*25, 512, 131072, stream>>>(regA, wqkvT, nullptr, XQKV,
                                             nullptr, nullptr, nullptr, 6272, 6272, 2048, 25);

  // fused post weight transposes (o, w1f, w2f) — reuses wqkvT region
  transpose_cast3<<<dim3(64,64,3), 256, 0, stream>>>(
      ow,  oT,   2048, 2048,
      w1f, w1fT, 2048, 1024,
      w2f, w2fT, 1024, 2048);

  // sequential TTT scan (MFMA formulation) -> ybb (bf16)
  ttt_scan<<<128, 512, 0, stream>>>(XQKV, ropec, ropes, tokb, tnw, tnb, lrb, W1i, b1i, ybb);

  // post-LN + O-projection + residual(enc) -> y2b (bf16)
  ln_rowb<<<2048, 256, 0, stream>>>(ybb, postw, postb, 1e-6f, regA);
  gemm256<1><<<32*8, 512, 131072, stream>>>(regA, oT, nullptr, y2b,
                                            nullptr, enc, nullptr, 2048, 2048, 2048, 8);

  // FFN
  ln_rowb<<<2048, 256, 0, stream>>>(y2b, flnw, flnb, 1e-6f, regA);
  gemm256<2><<<32*4, 512, 131072, stream>>>(regA, w1fT, nullptr, hbf,
                                            b1f, nullptr, nullptr, 1024, 1024, 2048, 4);
  gemm256<3><<<32*8, 512, 131072, stream>>>(hbf, w2fT, out, nullptr,
                                            b2f, nullptr, y2b, 2048, 2048, 1024, 8);
}

// Round 13
// 747.125 us; speedup vs baseline: 2.1013x; 1.0028x over previous
//
#include <hip/hip_runtime.h>

typedef unsigned short u16;
typedef __attribute__((ext_vector_type(8))) short short8;
typedef __attribute__((ext_vector_type(8))) unsigned short ushort8;
typedef __attribute__((ext_vector_type(4))) unsigned short us4;
typedef __attribute__((ext_vector_type(4))) float f32x4;
typedef __attribute__((ext_vector_type(2))) float f32x2;
typedef __attribute__((ext_vector_type(2))) unsigned int uint2v;

#define DEV __device__ __forceinline__

DEV float bf2f(u16 u){ union{unsigned int i; float f;} v; v.i = ((unsigned int)u)<<16u; return v.f; }
DEV u16 f2bf(float f){ union{float f; unsigned int i;} v; v.f=f; unsigned int r = v.i + 0x7FFFu + ((v.i>>16)&1u); return (u16)(r>>16); }

DEV void gload16(const u16* g, u16* l){
  __builtin_amdgcn_global_load_lds((const __attribute__((address_space(1))) void*)g,
                                   (__attribute__((address_space(3))) void*)l, 16, 0, 0);
}

DEV float wsum(float v){
  v += __shfl_xor(v, 32, 64);
  v += __shfl_xor(v, 16, 64);
  v += __shfl_xor(v, 8, 64);
  v += __shfl_xor(v, 4, 64);
  v += __shfl_xor(v, 2, 64);
  v += __shfl_xor(v, 1, 64);
  return v;
}

// sum over the 4 lanes sharing (lane&15). permlane pair-sum is
// orientation-agnostic (a[0]+a[1] == v + v[lane^k]) -> safe. (R2-verified.)
#if __has_builtin(__builtin_amdgcn_permlane16_swap) && __has_builtin(__builtin_amdgcn_permlane32_swap)
DEV float qsum(float v){
  unsigned u = __float_as_uint(v);
  uint2v a = __builtin_amdgcn_permlane16_swap(u, u, false, false);
  float s = __uint_as_float(a[0]) + __uint_as_float(a[1]);
  unsigned u2 = __float_as_uint(s);
  uint2v bsw = __builtin_amdgcn_permlane32_swap(u2, u2, false, false);
  return __uint_as_float(bsw[0]) + __uint_as_float(bsw[1]);
}
#else
DEV float qsum(float v){
  v += __shfl_xor(v, 16, 64);
  v += __shfl_xor(v, 32, 64);
  return v;
}
#endif

// exact element v[lane^32]: proven shfl only (R3 post-mortem).
DEV float swap32(float v){ return __shfl_xor(v, 32, 64); }

// raw workgroup barrier: drain own LDS ops only
#define BARS() do{ asm volatile("s_waitcnt lgkmcnt(0)" ::: "memory"); \
  __builtin_amdgcn_s_barrier(); __builtin_amdgcn_sched_barrier(0); }while(0)

// ---------------- LN over rows of 2048 (f32 in), one row per WAVE ----------------
__global__ __launch_bounds__(256) void ln_row(
    const float* __restrict__ in, const float* __restrict__ w, const float* __restrict__ bb,
    float eps, u16* __restrict__ outb)
{
  const int wv = threadIdx.x>>6, lane = threadIdx.x&63;
  const int row = blockIdx.x*4 + wv;
  const float* p = in + (size_t)row*2048 + lane*4;
  f32x4 a[8];
  #pragma unroll
  for(int j=0;j<8;j++) a[j] = *(const f32x4*)(p + j*256);
  float s = 0.f;
  #pragma unroll
  for(int j=0;j<8;j++) s += a[j][0]+a[j][1]+a[j][2]+a[j][3];
  s = wsum(s);
  float mu = s*(1.f/2048.f);
  float vs = 0.f;
  #pragma unroll
  for(int j=0;j<8;j++)
    #pragma unroll
    for(int r=0;r<4;r++){ float d=a[j][r]-mu; vs += d*d; }
  vs = wsum(vs);
  float rstd = rsqrtf(vs*(1.f/2048.f) + eps);
  #pragma unroll
  for(int j=0;j<8;j++){
    f32x4 wj = *(const f32x4*)(w  + j*256 + lane*4);
    f32x4 bj = *(const f32x4*)(bb + j*256 + lane*4);
    us4 o;
    #pragma unroll
    for(int r=0;r<4;r++) o[r] = f2bf((a[j][r]-mu)*rstd*wj[r] + bj[r]);
    *(us4*)(outb + (size_t)row*2048 + j*256 + lane*4) = o;
  }
}

// ---------------- LN over rows of 2048 (bf16 in), one row per WAVE ----------------
// bf16 loads vectorized as short8 (16B/lane, G13)
__global__ __launch_bounds__(256) void ln_rowb(
    const u16* __restrict__ in, const float* __restrict__ w, const float* __restrict__ bb,
    float eps, u16* __restrict__ outb)
{
  const int wv = threadIdx.x>>6, lane = threadIdx.x&63;
  const int row = blockIdx.x*4 + wv;
  const u16* p = in + (size_t)row*2048 + lane*8;
  float a[32];
  #pragma unroll
  for(int j=0;j<4;j++){
    ushort8 u = *(const ushort8*)(p + j*512);
    #pragma unroll
    for(int r=0;r<8;r++) a[j*8+r] = bf2f(u[r]);
  }
  float s = 0.f;
  #pragma unroll
  for(int e=0;e<32;e++) s += a[e];
  s = wsum(s);
  float mu = s*(1.f/2048.f);
  float vs = 0.f;
  #pragma unroll
  for(int e=0;e<32;e++){ float d=a[e]-mu; vs += d*d; }
  vs = wsum(vs);
  float rstd = rsqrtf(vs*(1.f/2048.f) + eps);
  #pragma unroll
  for(int j=0;j<4;j++){
    f32x4 w0 = *(const f32x4*)(w  + j*512 + lane*8);
    f32x4 w1 = *(const f32x4*)(w  + j*512 + lane*8 + 4);
    f32x4 b0 = *(const f32x4*)(bb + j*512 + lane*8);
    f32x4 b1 = *(const f32x4*)(bb + j*512 + lane*8 + 4);
    ushort8 o;
    #pragma unroll
    for(int r=0;r<4;r++) o[r]   = f2bf((a[j*8+r]-mu)*rstd*w0[r] + b0[r]);
    #pragma unroll
    for(int r=0;r<4;r++) o[r+4] = f2bf((a[j*8+4+r]-mu)*rstd*w1[r] + b1[r]);
    *(ushort8*)(outb + (size_t)row*2048 + j*512 + lane*8) = o;
  }
}

// ---------------- transpose + cast fp32 (K x N) -> bf16 (N x K), 3 tensors ----------------
__global__ __launch_bounds__(256) void transpose_cast3(
    const float* __restrict__ s0, u16* __restrict__ d0v, int K0, int N0,
    const float* __restrict__ s1, u16* __restrict__ d1v, int K1, int N1,
    const float* __restrict__ s2, u16* __restrict__ d2v, int K2, int N2)
{
  const int z = blockIdx.z;
  const float* src = (z==0)? s0 : (z==1)? s1 : s2;
  u16* dst = (z==0)? d0v : (z==1)? d1v : d2v;
  const int K = (z==0)? K0 : (z==1)? K1 : K2;
  const int N = (z==0)? N0 : (z==1)? N1 : N2;
  const int kb = blockIdx.x*32, nb = blockIdx.y*32;
  if (kb >= K || nb >= N) return;
  __shared__ float tile[32][33];
  const int tx = threadIdx.x & 31, ty = threadIdx.x >> 5; // 32 x 8
  #pragma unroll
  for(int i=0;i<4;i++){
    int k = ty + i*8;
    tile[k][tx] = src[(size_t)(kb+k)*N + nb + tx];
  }
  __syncthreads();
  #pragma unroll
  for(int i=0;i<4;i++){
    int nn = ty + i*8;
    dst[(size_t)(nb+nn)*K + kb + tx] = f2bf(tile[tx][nn]);
  }
}

// cast lr_w (32 x 2048) into rows [0..31] of a 256x2048 block, zero the rest
__global__ __launch_bounds__(256) void cast_lrw(const float* __restrict__ lrw, u16* __restrict__ dst)
{
  int i = blockIdx.x*256 + threadIdx.x;       // 256*2048 total
  if (i < 32*2048) dst[i] = f2bf(lrw[i]);
  else dst[i] = 0;
}

// rope tables (pos 0..15, d 0..63) + tok vector
__global__ void rope_init(const float* __restrict__ tio, float* __restrict__ cosb,
                          float* __restrict__ sinb, float* __restrict__ tokb)
{
  int t = blockIdx.x*256 + threadIdx.x;
  if (t < 1024){
    int p = t>>6, d = t&63;
    float inv = powf(10000.f, -(float)(2*(d&31))/64.f);
    float fr = (float)p * inv;
    cosb[t] = cosf(fr);
    sinb[t] = sinf(fr);
  }
  if (blockIdx.x==0 && threadIdx.x<16)
    tokb[threadIdx.x] = fmaxf(1.f/(float)(threadIdx.x+1) + tio[threadIdx.x], 0.f);
}

// ================== 256x256 8-phase bf16 GEMM (BK=64, 8 waves) ==================
// EPI: 1 = +resid(f32) -> bf16; 2 = +bias,relu -> bf16; 3 = +bias,+residb(bf16) -> f32;
//      4 = plain -> bf16
#define MM(MI,NI,AA,BB) acc[MI][NI] = __builtin_amdgcn_mfma_f32_16x16x32_bf16(AA, BB, acc[MI][NI], 0, 0, 0)

#define RD_A(D,KH,MF) (*(const short8*)(ldsb + ((D)<<16) + ((KH)<<14) + (wm<<13) + ((MF)<<10) + loff))
#define RD_B(D,KH,NF) (*(const short8*)(ldsb + ((D)<<16) + 32768 + ((KH)<<14) + (wn<<12) + ((NF)<<10) + loff))

#define PHASE(D,KH,MH,RB,STG,VM) { \
  __builtin_amdgcn_sched_barrier(0); \
  if (RB){ b0 = RD_B(D,KH,0); b1 = RD_B(D,KH,1); b2 = RD_B(D,KH,2); b3 = RD_B(D,KH,3); } \
  short8 a0 = RD_A(D,KH,4*(MH)+0); \
  short8 a1 = RD_A(D,KH,4*(MH)+1); \
  short8 a2 = RD_A(D,KH,4*(MH)+2); \
  short8 a3 = RD_A(D,KH,4*(MH)+3); \
  STG; \
  __builtin_amdgcn_sched_barrier(0); \
  __builtin_amdgcn_s_barrier(); \
  asm volatile("s_waitcnt lgkmcnt(0)" ::: "memory"); \
  __builtin_amdgcn_sched_barrier(0); \
  __builtin_amdgcn_s_setprio(1); \
  MM(4*(MH)+0,0,a0,b0); MM(4*(MH)+1,0,a1,b0); MM(4*(MH)+2,0,a2,b0); MM(4*(MH)+3,0,a3,b0); \
  MM(4*(MH)+0,1,a0,b1); MM(4*(MH)+1,1,a1,b1); MM(4*(MH)+2,1,a2,b1); MM(4*(MH)+3,1,a3,b1); \
  MM(4*(MH)+0,2,a0,b2); MM(4*(MH)+1,2,a1,b2); MM(4*(MH)+2,2,a2,b2); MM(4*(MH)+3,2,a3,b2); \
  MM(4*(MH)+0,3,a0,b3); MM(4*(MH)+1,3,a1,b3); MM(4*(MH)+2,3,a2,b3); MM(4*(MH)+3,3,a3,b3); \
  __builtin_amdgcn_s_setprio(0); \
  if (VM){ asm volatile("s_waitcnt vmcnt(8)" ::: "memory"); } \
  __builtin_amdgcn_sched_barrier(0); \
  __builtin_amdgcn_s_barrier(); \
}

template<int EPI>
__global__ __launch_bounds__(512, 2) void gemm256(
    const u16* __restrict__ A, const u16* __restrict__ Bt,
    float* __restrict__ C, u16* __restrict__ Cb,
    const float* __restrict__ bias, const float* __restrict__ resid,
    const u16* __restrict__ residb,
    int Nld, int Nreal, int K, int ntN)
{
  extern __shared__ u16 lds[];
  const int t = threadIdx.x, lane = t&63, wv = t>>6;
  const int wm = wv>>2, wn = wv&3;          // 2 (M) x 4 (N) waves
  const int fr = lane&15, kq = lane>>4;

  int bid = blockIdx.x;
  {
    int nwg = gridDim.x;                    // bijective XCD swizzle
    int q = nwg>>3, r = nwg&7;
    int x = bid&7, l = bid>>3;
    bid = (x<r) ? (x*(q+1)+l) : (r*(q+1)+(x-r)*q+l);
  }
  const int bm = bid/ntN, bn = bid%ntN;

  f32x4 acc[8][4];
  #pragma unroll
  for(int i=0;i<8;i++)
    #pragma unroll
    for(int j=0;j<4;j++) acc[i][j]=(f32x4){0.f,0.f,0.f,0.f};

  const u16* gA = A  + (size_t)(bm*256)*K;
  const u16* gB = Bt + (size_t)(bn*256)*K;

  const int Ls   = (t&7) ^ ((t>>3)&7);
  const int rstg = ((t>>3)<<1) | (Ls>>2);
  const int cstg = (Ls&3)<<3;
  u16* const ldsw = lds + (wv<<9);

  const int Plane = (((fr&1)<<2) | kq) ^ (fr>>1);
  const int loff  = ((fr>>1)<<7) | (Plane<<4);
  const char* const ldsb = (const char*)lds;

  auto stA = [&](int d, int kh, int kts){
    u16* lb = ldsw + (d<<15) + (kh<<13);
    const u16* g = gA + (size_t)rstg*K + kts + (kh<<5) + cstg;
    gload16(g, lb);
    gload16(g + ((size_t)K<<7), lb + 4096);
  };
  auto stB = [&](int d, int kh, int kts){
    u16* lb = ldsw + (d<<15) + 16384 + (kh<<13);
    const u16* g = gB + (size_t)rstg*K + kts + (kh<<5) + cstg;
    gload16(g, lb);
    gload16(g + ((size_t)K<<7), lb + 4096);
  };

  stA(0,0,0); stB(0,0,0); stA(0,1,0); stB(0,1,0); stA(1,0,64); stB(1,0,64);
  asm volatile("s_waitcnt vmcnt(8)" ::: "memory");
  __builtin_amdgcn_sched_barrier(0);
  __builtin_amdgcn_s_barrier();

  for (int kt = 0; kt < K; kt += 128){
    const int ktp = (kt+128 < K) ? kt+128 : 0;
    const int ktq = (kt+192 < K) ? kt+192 : kt+192-K;
    short8 b0={0},b1={0},b2={0},b3={0};
    PHASE(0,0,0,1, stA(1,1,kt+64), 0)
    PHASE(0,0,1,0, stB(1,1,kt+64), 1)
    PHASE(0,1,0,1, stA(0,0,ktp),   0)
    PHASE(0,1,1,0, stB(0,0,ktp),   1)
    PHASE(1,0,0,1, stA(0,1,ktp),   0)
    PHASE(1,0,1,0, stB(0,1,ktp),   1)
    PHASE(1,1,0,1, stA(1,0,ktq),   0)
    PHASE(1,1,1,0, stB(1,0,ktq),   1)
  }

  const int cr = (lane>>4)<<2, cc = lane&15;
  #pragma unroll
  for(int mi=0;mi<8;mi++){
    #pragma unroll
    for(int ni=0;ni<4;ni++){
      const int row0 = bm*256 + wm*128 + mi*16 + cr;
      const int col  = bn*256 + wn*64  + ni*16 + cc;
      if (col < Nreal){
        #pragma unroll
        for(int rr=0;rr<4;rr++){
          size_t idx = (size_t)(row0+rr)*Nld + col;
          float v = acc[mi][ni][rr];
          if (EPI==1) { v += resid[idx]; Cb[idx] = f2bf(v); }
          else if (EPI==2){ v += bias[col]; v = fmaxf(v, 0.f); Cb[idx] = f2bf(v); }
          else if (EPI==3){ v += bias[col]; v += bf2f(residb[idx]); C[idx] = v; }
          else { Cb[idx] = f2bf(v); }   // EPI==4
        }
      }
    }
  }
}

// ================== MFMA TTT scan ==================
// R6-proven role layout (best measured scan: 248.0 us) + bf16 Y epilogue:
//  X: waves 0,1 chain (dup x2) -> gradTbf[n&1]; wave 4: Zq(n)+do_out(n-1);
//     wave 7: At -> etaA[n&1]; stagers {2,3,5,6} stage(n+1) -> slot (n+1)%3,
//     prefetch n+2.
//  Y: stagers: W1 MFMA update (own mtile sm) -> W1bf[(n&1)^1]; wave 7: b1.
//     waves 0,1,4 idle.
#define W1LD 72
#define XLD  72
#define GTLD 40
#define EKLD 40
#define EALD 40
#define TD2  68

__global__ __launch_bounds__(512, 1) void ttt_scan(
    const u16* __restrict__ XQKV,   // 8192 x 6272 bf16: [q|k|v|lr_pre(32)+pad]
    const float* __restrict__ ropec, const float* __restrict__ ropes,
    const float* __restrict__ tokp,
    const float* __restrict__ nw, const float* __restrict__ nb,
    const float* __restrict__ lrb,
    const float* __restrict__ W1i,  // NH x 64 x 64  (W1i[h][k][d])
    const float* __restrict__ b1i,  // NH x 64
    u16* __restrict__ Y)            // 8192 x 2048 bf16
{
  const int blk = blockIdx.x, b = blk>>5, h = blk&31;
  const int t = threadIdx.x, lane = t&63, wv = t>>6;
  const int fr = lane&15, quad = lane>>4;
  const bool isStager = (wv==2)||(wv==3)||(wv==5)||(wv==6);
  const int sm = (wv>=5)? wv-3 : wv-2;   // 0..3 for stagers (mtile / row-group)

  __shared__ u16 W1bf[2][64*W1LD];     // double-buffered W1t[d][k] bf16
  __shared__ u16 xqbf[3][16*XLD];      // [i][k], slot = minibatch%3
  __shared__ u16 xkbf[3][16*XLD];
  __shared__ u16 exkT[3][64*EKLD];     // [k][j] = -e_j * xk[j][k]
  __shared__ u16 gradTbf[2][64*GTLD];  // [d][j], parity = step&1
  __shared__ u16 etaA[2][16*EALD];     // [i][j], parity = step&1
  __shared__ float tgT2[3][16*TD2];    // [i][d] = (v - xk)[i][d]
  __shared__ float xqT2[3][16*TD2];    // [i][d]
  __shared__ float b1s[64];
  __shared__ float lrs[3][16];

  const float lrbh = lrb[h];
  const float ct = tokp[15]*(1.f/64.f);
  const float sg = (lane<32)? -1.f : 1.f;

  // loop-invariant LN params / tok in registers
  f32x2 lwr[16];
  #pragma unroll
  for(int m=0;m<4;m++)
    #pragma unroll
    for(int r=0;r<4;r++){
      int d = m*16+quad*4+r;
      lwr[m*4+r] = (f32x2){nw[h*64+d], nb[h*64+d]};
    }
  float tki[4];
  #pragma unroll
  for(int r=0;r<4;r++) tki[r] = tokp[quad*4+r];

  // stagers: rope tables for their 4 rows, W1 state (mtile sm), prefetch regs
  float ccj[4], ssj[4];
  f32x4 wf0, wf1, wf2, wf3;
  u16 Pq[4], Pk[4], Pv[4], Pl[4];
  if (isStager){
    #pragma unroll
    for(int j=0;j<4;j++){
      ccj[j] = ropec[(sm*4+j)*64 + lane];
      ssj[j] = ropes[(sm*4+j)*64 + lane];
    }
    const float* wsrc = W1i + (size_t)h*4096;
    #pragma unroll
    for(int r=0;r<4;r++){
      int d = sm*16+quad*4+r;
      wf0[r] = wsrc[( 0+fr)*64 + d];
      wf1[r] = wsrc[(16+fr)*64 + d];
      wf2[r] = wsrc[(32+fr)*64 + d];
      wf3[r] = wsrc[(48+fr)*64 + d];
    }
    #pragma unroll
    for(int r=0;r<4;r++){
      int d = sm*16+quad*4+r;
      W1bf[0][d*W1LD +  0 + fr] = f2bf(wf0[r]);
      W1bf[0][d*W1LD + 16 + fr] = f2bf(wf1[r]);
      W1bf[0][d*W1LD + 32 + fr] = f2bf(wf2[r]);
      W1bf[0][d*W1LD + 48 + fr] = f2bf(wf3[r]);
    }
  }
  // zero pads (cols [16,40) so K=32 fragments see zeros) — all buffers
  for(int i=t;i<64*24;i+=512){
    int rr=i/24, cp=16+i%24;
    gradTbf[0][rr*GTLD+cp]=0; gradTbf[1][rr*GTLD+cp]=0;
    exkT[0][rr*EKLD+cp]=0; exkT[1][rr*EKLD+cp]=0; exkT[2][rr*EKLD+cp]=0;
  }
  for(int i=t;i<16*24;i+=512){
    int rr=i/24, cp=16+i%24;
    etaA[0][rr*EALD+cp]=0; etaA[1][rr*EALD+cp]=0;
  }
  if (t<64) b1s[t]=b1i[h*64+t];

  // stager helpers: load minibatch n rows (sm*4..sm*4+3) into P; stage P -> slot
  auto loadP = [&](int n){
    const size_t rb = (size_t)b*2048 + n*16;
    #pragma unroll
    for(int j=0;j<4;j++){
      const u16* p = XQKV + (rb+sm*4+j)*6272 + h*64 + lane;
      Pq[j]=p[0]; Pk[j]=p[2048]; Pv[j]=p[4096];
      Pl[j]=XQKV[(rb+sm*4+j)*6272 + 6144 + h];
    }
  };
  auto stage4 = [&](int slot){
    #pragma unroll
    for(int j=0;j<4;j++){
      const int i = sm*4+j;
      float q=bf2f(Pq[j]), k=bf2f(Pk[j]), v=bf2f(Pv[j]);
      float qr = q*ccj[j] + sg*swap32(q)*ssj[j];
      float kr = k*ccj[j] + sg*swap32(k)*ssj[j];
      float lr = 1.f/(1.f + expf(-(bf2f(Pl[j]) + lrbh)));
      xqbf[slot][i*XLD+lane] = f2bf(qr);
      xkbf[slot][i*XLD+lane] = f2bf(kr);
      exkT[slot][lane*EKLD+i] = f2bf(-ct*lr*kr);
      tgT2[slot][i*TD2+lane] = v - kr;
      xqT2[slot][i*TD2+lane] = qr;
      if (lane==0) lrs[slot][i]=lr;
    }
  };

  // prologue: stage minibatch 0 into slot 0; prefetch minibatch 1
  if (isStager){
    loadP(0);
    stage4(0);
    loadP(1);
  }
  __syncthreads();

  const f32x4 fzero = (f32x4){0.f,0.f,0.f,0.f};

  // wave-4 carried state (output pipeline depth 1)
  f32x4 zqP0=fzero, zqP1=fzero, zqP2=fzero, zqP3=fzero;
  f32x4 b1qP0=fzero, b1qP1=fzero, b1qP2=fzero, b1qP3=fzero;

  // output chain for step s: parity2 = s&1 (etaA/gradT), slot3 = s%3 (xqT2)
  auto do_out = [&](int p2, int p3, size_t rb){
    short8 be = *(const short8*)&etaA[p2][fr*EALD + quad*8];
    f32x4 c20,c21,c22,c23;
    c20 = __builtin_amdgcn_mfma_f32_16x16x32_bf16(*(const short8*)&gradTbf[p2][( 0+fr)*GTLD + quad*8], be, fzero, 0,0,0);
    c21 = __builtin_amdgcn_mfma_f32_16x16x32_bf16(*(const short8*)&gradTbf[p2][(16+fr)*GTLD + quad*8], be, fzero, 0,0,0);
    c22 = __builtin_amdgcn_mfma_f32_16x16x32_bf16(*(const short8*)&gradTbf[p2][(32+fr)*GTLD + quad*8], be, fzero, 0,0,0);
    c23 = __builtin_amdgcn_mfma_f32_16x16x32_bf16(*(const short8*)&gradTbf[p2][(48+fr)*GTLD + quad*8], be, fzero, 0,0,0);
    f32x4 xqv0 = *(const f32x4*)&xqT2[p3][fr*TD2 +  0 + quad*4];
    f32x4 xqv1 = *(const f32x4*)&xqT2[p3][fr*TD2 + 16 + quad*4];
    f32x4 xqv2 = *(const f32x4*)&xqT2[p3][fr*TD2 + 32 + quad*4];
    f32x4 xqv3 = *(const f32x4*)&xqT2[p3][fr*TD2 + 48 + quad*4];
    f32x4 zb0,zb1,zb2,zb3;
    float s1=0.f, s2=0.f;
    #pragma unroll
    for(int r=0;r<4;r++){
      zb0[r] = zqP0[r] + b1qP0[r] + c20[r];
      zb1[r] = zqP1[r] + b1qP1[r] + c21[r];
      zb2[r] = zqP2[r] + b1qP2[r] + c22[r];
      zb3[r] = zqP3[r] + b1qP3[r] + c23[r];
      s1 += zb0[r]+zb1[r]+zb2[r]+zb3[r];
      s2 += zb0[r]*zb0[r]+zb1[r]*zb1[r]+zb2[r]*zb2[r]+zb3[r]*zb3[r];
    }
    s1 = qsum(s1); s2 = qsum(s2);
    float mu = s1*(1.f/64.f);
    float var = s2*(1.f/64.f) - mu*mu;
    float rstd = rsqrtf(var + 1e-6f);
    #pragma unroll
    for(int m=0;m<4;m++){
      f32x4* zp = (m==0)?&zb0:(m==1)?&zb1:(m==2)?&zb2:&zb3;
      const f32x4* xp = (m==0)?&xqv0:(m==1)?&xqv1:(m==2)?&xqv2:&xqv3;
      us4 o;
      #pragma unroll
      for(int r=0;r<4;r++){
        f32x2 wb = lwr[m*4+r];
        float xh = ((*zp)[r] - mu)*rstd;
        o[r] = f2bf((*xp)[r] + xh*wb[0] + wb[1]);
      }
      *(us4*)&Y[(rb+fr)*2048 + h*64 + m*16 + quad*4] = o;
    }
  };

  int c3 = 0;   // n%3
  for(int n=0;n<128;n++){
    const int cur2 = n&1, pb2 = cur2^1;
    const int cur3 = c3;
    const int nxt3 = (c3==2)? 0 : c3+1;
    const int pb3  = (c3==0)? 2 : c3-1;
    const size_t rbase = (size_t)b*2048 + n*16;

    // ---------------- region X ----------------
    if (wv < 2){
      f32x4 b1v0 = *(const f32x4*)&b1s[ 0+quad*4];
      f32x4 b1v1 = *(const f32x4*)&b1s[16+quad*4];
      f32x4 b1v2 = *(const f32x4*)&b1s[32+quad*4];
      f32x4 b1v3 = *(const f32x4*)&b1s[48+quad*4];
      f32x4 tgv0 = *(const f32x4*)&tgT2[cur3][fr*TD2 +  0 + quad*4];
      f32x4 tgv1 = *(const f32x4*)&tgT2[cur3][fr*TD2 + 16 + quad*4];
      f32x4 tgv2 = *(const f32x4*)&tgT2[cur3][fr*TD2 + 32 + quad*4];
      f32x4 tgv3 = *(const f32x4*)&tgT2[cur3][fr*TD2 + 48 + quad*4];
      // Zk^T = W1t (x) xk : C[d][i], full 64x16 (dup x2: waves 0,1)
      short8 bk0 = *(const short8*)&xkbf[cur3][fr*XLD + quad*8];
      short8 bk1 = *(const short8*)&xkbf[cur3][fr*XLD + 32 + quad*8];
      f32x4 z0,z1,z2,z3;
      z0 = __builtin_amdgcn_mfma_f32_16x16x32_bf16(*(const short8*)&W1bf[cur2][( 0+fr)*W1LD + quad*8],      bk0, fzero, 0,0,0);
      z0 = __builtin_amdgcn_mfma_f32_16x16x32_bf16(*(const short8*)&W1bf[cur2][( 0+fr)*W1LD + 32 + quad*8], bk1, z0,    0,0,0);
      z1 = __builtin_amdgcn_mfma_f32_16x16x32_bf16(*(const short8*)&W1bf[cur2][(16+fr)*W1LD + quad*8],      bk0, fzero, 0,0,0);
      z1 = __builtin_amdgcn_mfma_f32_16x16x32_bf16(*(const short8*)&W1bf[cur2][(16+fr)*W1LD + 32 + quad*8], bk1, z1,    0,0,0);
      z2 = __builtin_amdgcn_mfma_f32_16x16x32_bf16(*(const short8*)&W1bf[cur2][(32+fr)*W1LD + quad*8],      bk0, fzero, 0,0,0);
      z2 = __builtin_amdgcn_mfma_f32_16x16x32_bf16(*(const short8*)&W1bf[cur2][(32+fr)*W1LD + 32 + quad*8], bk1, z2,    0,0,0);
      z3 = __builtin_amdgcn_mfma_f32_16x16x32_bf16(*(const short8*)&W1bf[cur2][(48+fr)*W1LD + quad*8],      bk0, fzero, 0,0,0);
      z3 = __builtin_amdgcn_mfma_f32_16x16x32_bf16(*(const short8*)&W1bf[cur2][(48+fr)*W1LD + 32 + quad*8], bk1, z3,    0,0,0);
      // LN-l2 backward
      f32x4 xh0,xh1,xh2,xh3;
      {
        float s1=0.f, s2=0.f;
        #pragma unroll
        for(int r=0;r<4;r++){
          z0[r] += b1v0[r];
          z1[r] += b1v1[r];
          z2[r] += b1v2[r];
          z3[r] += b1v3[r];
          s1 += z0[r]+z1[r]+z2[r]+z3[r];
          s2 += z0[r]*z0[r]+z1[r]*z1[r]+z2[r]*z2[r]+z3[r]*z3[r];
        }
        s1 = qsum(s1); s2 = qsum(s2);
        float mu = s1*(1.f/64.f);
        float var = s2*(1.f/64.f) - mu*mu;
        float rstd = rsqrtf(var + 1e-6f);
        float u1=0.f, u2=0.f;
        #pragma unroll
        for(int m=0;m<4;m++){
          f32x4* zp = (m==0)?&z0:(m==1)?&z1:(m==2)?&z2:&z3;
          f32x4* xp = (m==0)?&xh0:(m==1)?&xh1:(m==2)?&xh2:&xh3;
          const f32x4* tp = (m==0)?&tgv0:(m==1)?&tgv1:(m==2)?&tgv2:&tgv3;
          #pragma unroll
          for(int r=0;r<4;r++){
            f32x2 wb = lwr[m*4+r];
            float xh = ((*zp)[r] - mu)*rstd;
            float gx = (wb[0]*xh + wb[1] - (*tp)[r])*wb[0];
            (*xp)[r] = xh;
            (*zp)[r] = gx;
            u1 += gx; u2 += gx*xh;
          }
        }
        u1 = qsum(u1); u2 = qsum(u2);
        const float c64 = rstd*(1.f/64.f);
        #pragma unroll
        for(int m=0;m<4;m++){
          f32x4* zp = (m==0)?&z0:(m==1)?&z1:(m==2)?&z2:&z3;
          f32x4* xp = (m==0)?&xh0:(m==1)?&xh1:(m==2)?&xh2:&xh3;
          #pragma unroll
          for(int r=0;r<4;r++)
            (*zp)[r] = (64.f*(*zp)[r] - u1 - (*xp)[r]*u2)*c64;   // gradT
        }
      }
      // wave0 writes mtiles 0,1; wave1 writes 2,3
      f32x4 zA = (wv==0)? z0 : z2;
      f32x4 zB = (wv==0)? z1 : z3;
      const int rb0 = wv*32;
      #pragma unroll
      for(int r=0;r<4;r++){
        gradTbf[cur2][(rb0+quad*4+r)*GTLD + fr]    = f2bf(zA[r]);
        gradTbf[cur2][(rb0+16+quad*4+r)*GTLD + fr] = f2bf(zB[r]);
      }
    }
    else if (wv == 4){
      // Zq(n): independent MFMAs into fresh regs
      short8 bq0 = *(const short8*)&xqbf[cur3][fr*XLD + quad*8];
      short8 bq1 = *(const short8*)&xqbf[cur3][fr*XLD + 32 + quad*8];
      f32x4 zqN0,zqN1,zqN2,zqN3;
      zqN0 = __builtin_amdgcn_mfma_f32_16x16x32_bf16(*(const short8*)&W1bf[cur2][( 0+fr)*W1LD + quad*8],      bq0, fzero, 0,0,0);
      zqN0 = __builtin_amdgcn_mfma_f32_16x16x32_bf16(*(const short8*)&W1bf[cur2][( 0+fr)*W1LD + 32 + quad*8], bq1, zqN0,  0,0,0);
      zqN1 = __builtin_amdgcn_mfma_f32_16x16x32_bf16(*(const short8*)&W1bf[cur2][(16+fr)*W1LD + quad*8],      bq0, fzero, 0,0,0);
      zqN1 = __builtin_amdgcn_mfma_f32_16x16x32_bf16(*(const short8*)&W1bf[cur2][(16+fr)*W1LD + 32 + quad*8], bq1, zqN1,  0,0,0);
      zqN2 = __builtin_amdgcn_mfma_f32_16x16x32_bf16(*(const short8*)&W1bf[cur2][(32+fr)*W1LD + quad*8],      bq0, fzero, 0,0,0);
      zqN2 = __builtin_amdgcn_mfma_f32_16x16x32_bf16(*(const short8*)&W1bf[cur2][(32+fr)*W1LD + 32 + quad*8], bq1, zqN2,  0,0,0);
      zqN3 = __builtin_amdgcn_mfma_f32_16x16x32_bf16(*(const short8*)&W1bf[cur2][(48+fr)*W1LD + quad*8],      bq0, fzero, 0,0,0);
      zqN3 = __builtin_amdgcn_mfma_f32_16x16x32_bf16(*(const short8*)&W1bf[cur2][(48+fr)*W1LD + 32 + quad*8], bq1, zqN3,  0,0,0);
      // output of step n-1
      if (n > 0) do_out(pb2, pb3, rbase - 16);
      // rotate pipeline state
      zqP0=zqN0; zqP1=zqN1; zqP2=zqN2; zqP3=zqN3;
      b1qP0 = *(const f32x4*)&b1s[ 0+quad*4];   // b1 pre-update for step n
      b1qP1 = *(const f32x4*)&b1s[16+quad*4];
      b1qP2 = *(const f32x4*)&b1s[32+quad*4];
      b1qP3 = *(const f32x4*)&b1s[48+quad*4];
    }
    else if (wv == 7){
      // At = xq (x) xk : C[i][j] -> etaA[cur2]
      short8 aq0 = *(const short8*)&xqbf[cur3][fr*XLD + quad*8];
      short8 aq1 = *(const short8*)&xqbf[cur3][fr*XLD + 32 + quad*8];
      short8 bk0 = *(const short8*)&xkbf[cur3][fr*XLD + quad*8];
      short8 bk1 = *(const short8*)&xkbf[cur3][fr*XLD + 32 + quad*8];
      f32x4 at;
      at = __builtin_amdgcn_mfma_f32_16x16x32_bf16(aq0, bk0, fzero, 0,0,0);
      at = __builtin_amdgcn_mfma_f32_16x16x32_bf16(aq1, bk1, at,    0,0,0);
      float lrj = lrs[cur3][fr]*(1.f/64.f);
      #pragma unroll
      for(int r=0;r<4;r++){
        int i = quad*4 + r;
        float val = (fr <= i) ? -tki[r]*lrj*(1.f + at[r]) : 0.f;
        etaA[cur2][i*EALD + fr] = f2bf(val);
      }
    }
    else {
      // stagers {2,3,5,6}: stage(n+1) into slot nxt3; prefetch minibatch n+2
      if (n < 127) stage4(nxt3);
      if (n < 126) loadP(n+2);
    }
    BARS();

    // ---------------- region Y ----------------
    if (isStager){
      // W1 update: wave owns mtile sm, tiles n=0..3
      short8 ga = *(const short8*)&gradTbf[cur2][(sm*16+fr)*GTLD + quad*8];
      short8 e0 = *(const short8*)&exkT[cur3][( 0+fr)*EKLD + quad*8];
      short8 e1 = *(const short8*)&exkT[cur3][(16+fr)*EKLD + quad*8];
      short8 e2 = *(const short8*)&exkT[cur3][(32+fr)*EKLD + quad*8];
      short8 e3 = *(const short8*)&exkT[cur3][(48+fr)*EKLD + quad*8];
      wf0 = __builtin_amdgcn_mfma_f32_16x16x32_bf16(ga, e0, wf0, 0,0,0);
      wf1 = __builtin_amdgcn_mfma_f32_16x16x32_bf16(ga, e1, wf1, 0,0,0);
      wf2 = __builtin_amdgcn_mfma_f32_16x16x32_bf16(ga, e2, wf2, 0,0,0);
      wf3 = __builtin_amdgcn_mfma_f32_16x16x32_bf16(ga, e3, wf3, 0,0,0);
      #pragma unroll
      for(int r=0;r<4;r++){
        int d = sm*16+quad*4+r;
        W1bf[pb2][d*W1LD +  0 + fr] = f2bf(wf0[r]);
        W1bf[pb2][d*W1LD + 16 + fr] = f2bf(wf1[r]);
        W1bf[pb2][d*W1LD + 32 + fr] = f2bf(wf2[r]);
        W1bf[pb2][d*W1LD + 48 + fr] = f2bf(wf3[r]);
      }
    }
    else if (wv == 7){
      // b1 update: b1s[d] -= ct * sum_j lrs[j] * gradT[d][j]
      const int d = lane;
      short8 g0 = *(const short8*)&gradTbf[cur2][d*GTLD + 0];
      short8 g1 = *(const short8*)&gradTbf[cur2][d*GTLD + 8];
      float s = 0.f;
      #pragma unroll
      for(int j=0;j<8;j++) s += lrs[cur3][j]   * bf2f((u16)g0[j]);
      #pragma unroll
      for(int j=0;j<8;j++) s += lrs[cur3][8+j] * bf2f((u16)g1[j]);
      b1s[d] -= ct * s;
    }
    BARS();
    c3 = nxt3;
  }

  // epilogue: output of the last step (n=127): parity2 = 1, slot3 = 127%3 = 1
  if (wv == 4) do_out(1, 1, (size_t)b*2048 + 127*16);
}

// ---------------- host launch ----------------
extern "C" void kernel_launch(void* const* d_in, const int* in_sizes, int n_in,
                              void* d_out, int out_size, void* d_ws, size_t ws_size,
                              hipStream_t stream)
{
  const float* enc   = (const float*)d_in[0];
  const float* ln1w  = (const float*)d_in[1];
  const float* ln1b  = (const float*)d_in[2];
  const float* qw    = (const float*)d_in[3];
  const float* kw    = (const float*)d_in[4];
  const float* vw    = (const float*)d_in[5];
  const float* ow    = (const float*)d_in[6];
  const float* lrw   = (const float*)d_in[7];
  const float* lrb   = (const float*)d_in[8];
  const float* tio   = (const float*)d_in[9];
  const float* tnw   = (const float*)d_in[10];
  const float* tnb   = (const float*)d_in[11];
  const float* W1i   = (const float*)d_in[12];
  const float* b1i   = (const float*)d_in[13];
  const float* postw = (const float*)d_in[14];
  const float* postb = (const float*)d_in[15];
  const float* flnw  = (const float*)d_in[16];
  const float* flnb  = (const float*)d_in[17];
  const float* w1f   = (const float*)d_in[18];
  const float* b1f   = (const float*)d_in[19];
  const float* w2f   = (const float*)d_in[20];
  const float* b2f   = (const float*)d_in[21];
  float* out = (float*)d_out;

  char* ws = (char*)d_ws;
  size_t off = 0;
  auto alloc = [&](size_t bytes)->void*{ void* p = ws + off; off += (bytes + 255) & ~(size_t)255; return p; };
  u16*   regA  = (u16*)  alloc(8192ull*2048*2);   // x_bf -> ypost_bf -> z_bf
  u16*   wqkvT = (u16*)  alloc(6400ull*2048*2);   // [qT|kT|vT|lr(32)+zeros..6400); later oT/w1fT/w2fT
  u16*   XQKV  = (u16*)  alloc(8192ull*6272*2);   // later: h_bf
  u16*   ybb   = (u16*)  alloc(8192ull*2048*2);   // scan output y (bf16)
  u16*   y2b   = (u16*)  alloc(8192ull*2048*2);   // y2 = o-proj + enc (bf16)
  float* ropec = (float*)alloc(1024*4);
  float* ropes = (float*)alloc(1024*4);
  float* tokb  = (float*)alloc(64*4);

  u16* oT   = wqkvT;
  u16* w1fT = wqkvT + 2048ull*2048;
  u16* w2fT = w1fT + 1024ull*2048;
  u16* hbf  = XQKV;

  static bool s_attr = false;
  if (!s_attr){
    s_attr = true;
    (void)hipFuncSetAttribute(reinterpret_cast<const void*>(gemm256<4>), hipFuncAttributeMaxDynamicSharedMemorySize, 131072);
    (void)hipFuncSetAttribute(reinterpret_cast<const void*>(gemm256<1>), hipFuncAttributeMaxDynamicSharedMemorySize, 131072);
    (void)hipFuncSetAttribute(reinterpret_cast<const void*>(gemm256<2>), hipFuncAttributeMaxDynamicSharedMemorySize, 131072);
    (void)hipFuncSetAttribute(reinterpret_cast<const void*>(gemm256<3>), hipFuncAttributeMaxDynamicSharedMemorySize, 131072);
  }

  rope_init<<<4, 256, 0, stream>>>(tio, ropec, ropes, tokb);

  // fused pre-GEMM weight transposes (q,k,v)
  transpose_cast3<<<dim3(64,64,3), 256, 0, stream>>>(
      qw, wqkvT,                2048, 2048,
      kw, wqkvT + 2048ull*2048, 2048, 2048,
      vw, wqkvT + 4096ull*2048, 2048, 2048);
  cast_lrw<<<2048, 256, 0, stream>>>(lrw, wqkvT + 6144ull*2048);

  ln_row<<<2048, 256, 0, stream>>>(enc, ln1w, ln1b, 1e-5f, regA);

  // QKV + lr projection: logical N=6400 (25 tiles), real cols 6272, ldc 6272
  gemm256<4><<<32*25, 512, 131072, stream>>>(regA, wqkvT, nullptr, XQKV,
                                             nullptr, nullptr, nullptr, 6272, 6272, 2048, 25);

  // fused post weight transposes (o, w1f, w2f) — reuses wqkvT region
  transpose_cast3<<<dim3(64,64,3), 256, 0, stream>>>(
      ow,  oT,   2048, 2048,
      w1f, w1fT, 2048, 1024,
      w2f, w2fT, 1024, 2048);

  // sequential TTT scan (MFMA formulation) -> ybb (bf16)
  ttt_scan<<<128, 512, 0, stream>>>(XQKV, ropec, ropes, tokb, tnw, tnb, lrb, W1i, b1i, ybb);

  // post-LN + O-projection + residual(enc) -> y2b (bf16)
  ln_rowb<<<2048, 256, 0, stream>>>(ybb, postw, postb, 1e-6f, regA);
  gemm256<1><<<32*8, 512, 131072, stream>>>(regA, oT, nullptr, y2b,
                                            nullptr, enc, nullptr, 2048, 2048, 2048, 8);

  // FFN
  ln_rowb<<<2048, 256, 0, stream>>>(y2b, flnw, flnb, 1e-6f, regA);
  gemm256<2><<<32*4, 512, 131072, stream>>>(regA, w1fT, nullptr, hbf,
                                            b1f, nullptr, nullptr, 1024, 1024, 2048, 4);
  gemm256<3><<<32*8, 512, 131072, stream>>>(hbf, w2fT, out, nullptr,
                                            b2f, nullptr, y2b, 2048, 2048, 1024, 8);
}